// Round 1
// baseline (820.158 us; speedup 1.0000x reference)
//
#include <hip/hip_runtime.h>
#include <hip/hip_bf16.h>
#include <stdint.h>

typedef __attribute__((ext_vector_type(8))) short short8;
typedef __attribute__((ext_vector_type(4))) float f32x4;

#define LOG2E 1.44269504088896340736f

__device__ __forceinline__ unsigned short f2bf(float f) {
  union { float f; unsigned int u; } v; v.f = f;
  unsigned int r = v.u + 0x7FFFu + ((v.u >> 16) & 1u);
  return (unsigned short)(r >> 16);
}

#define GLOAD16(gsrc, ldst)                                                                  \
  __builtin_amdgcn_global_load_lds((const __attribute__((address_space(1))) void*)(gsrc),    \
                                   (__attribute__((address_space(3))) void*)(ldst), 16, 0, 0)

// ---------------- cast x (fp32 -> bf16), 4 elems/thread ----------------
__global__ __launch_bounds__(256) void cast_bf16_kernel(const float* __restrict__ in,
                                                        unsigned short* __restrict__ out) {
  int i = blockIdx.x * 256 + threadIdx.x;
  float4 v = ((const float4*)in)[i];
  ushort4 o;
  o.x = f2bf(v.x); o.y = f2bf(v.y); o.z = f2bf(v.z); o.w = f2bf(v.w);
  ((ushort4*)out)[i] = o;
}

// ---------------- transpose + cast W: [K][N] fp32 -> [N][K] bf16 ----------------
__global__ __launch_bounds__(256) void transpose_cast_kernel(const float* __restrict__ W,
                                                             unsigned short* __restrict__ Wt,
                                                             int K, int N) {
  __shared__ float tile[32][33];
  int n0 = blockIdx.x * 32, k0 = blockIdx.y * 32;
  int tx = threadIdx.x, ty = threadIdx.y;
#pragma unroll
  for (int j = 0; j < 32; j += 8)
    tile[ty + j][tx] = W[(size_t)(k0 + ty + j) * N + n0 + tx];
  __syncthreads();
#pragma unroll
  for (int j = 0; j < 32; j += 8)
    Wt[(size_t)(n0 + ty + j) * K + k0 + tx] = f2bf(tile[tx][ty + j]);
}

// ---------------- 128x128 tile GEMM mainloop (m97 structure) ----------------
// A: [M][K] bf16 row-major, Bt: [N][K] bf16 row-major. 256 threads, 4 waves (2x2),
// each wave computes a 64x64 subtile as 4x4 fragments of 16x16, BK=64.
__device__ __forceinline__ void gemm128_mainloop(const unsigned short* __restrict__ Ap,
                                                 const unsigned short* __restrict__ Bp,
                                                 unsigned short* a_lds, unsigned short* b_lds,
                                                 int K, int tid, f32x4 acc[4][4]) {
  int wid = tid >> 6, lane = tid & 63;
  int wr = wid >> 1, wc = wid & 1;
  int lg = lane >> 4, l15 = lane & 15;
  for (int k0 = 0; k0 < K; k0 += 64) {
    __syncthreads();  // protect previous iteration's LDS reads
#pragma unroll
    for (int it = 0; it < 4; ++it) {  // stage A tile 128x64 (linear LDS, width-16 DMA)
      int li = it * 256 + tid;
      int r = li >> 3, c = li & 7;
      GLOAD16(Ap + (size_t)r * K + k0 + c * 8, (char*)a_lds + li * 16);
    }
#pragma unroll
    for (int it = 0; it < 4; ++it) {  // stage B tile 128x64
      int li = it * 256 + tid;
      int r = li >> 3, c = li & 7;
      GLOAD16(Bp + (size_t)r * K + k0 + c * 8, (char*)b_lds + li * 16);
    }
    __syncthreads();  // vmcnt(0) drain at barrier
#pragma unroll
    for (int kc = 0; kc < 2; ++kc) {
      short8 af[4], bfv[4];
#pragma unroll
      for (int m = 0; m < 4; ++m)
        af[m] = *(const short8*)(a_lds + (wr * 64 + m * 16 + l15) * 64 + kc * 32 + lg * 8);
#pragma unroll
      for (int n = 0; n < 4; ++n)
        bfv[n] = *(const short8*)(b_lds + (wc * 64 + n * 16 + l15) * 64 + kc * 32 + lg * 8);
#pragma unroll
      for (int m = 0; m < 4; ++m)
#pragma unroll
        for (int n = 0; n < 4; ++n)
          acc[m][n] = __builtin_amdgcn_mfma_f32_16x16x32_bf16(af[m], bfv[n], acc[m][n], 0, 0, 0);
    }
  }
}

// ---------------- QKV GEMM: C[t][n] -> scatter q/k ([bh][t][d]) and v transposed ([bh][d][t]) ----------------
__global__ __launch_bounds__(256) void gemm_qkv_kernel(const unsigned short* __restrict__ A,
                                                       const unsigned short* __restrict__ Bt,
                                                       const float* __restrict__ bias,
                                                       unsigned short* __restrict__ qb,
                                                       unsigned short* __restrict__ kb,
                                                       unsigned short* __restrict__ vtb) {
  __shared__ unsigned short a_lds[128 * 64];
  __shared__ unsigned short b_lds[128 * 64];
  int bm = blockIdx.x, bn = blockIdx.y;
  int tid = threadIdx.x;
  f32x4 acc[4][4];
  f32x4 zero = {0.f, 0.f, 0.f, 0.f};
#pragma unroll
  for (int m = 0; m < 4; ++m)
#pragma unroll
    for (int n = 0; n < 4; ++n) acc[m][n] = zero;

  gemm128_mainloop(A + (size_t)bm * 128 * 2048, Bt + (size_t)bn * 128 * 2048,
                   a_lds, b_lds, 2048, tid, acc);

  int wid = tid >> 6, lane = tid & 63;
  int wr = wid >> 1, wc = wid & 1, lg = lane >> 4, l15 = lane & 15;
#pragma unroll
  for (int n = 0; n < 4; ++n) {
    int col = bn * 128 + wc * 64 + n * 16 + l15;  // in [0,6144)
    float bv = bias[col];
    int which = col >> 11;        // 0=q 1=k 2=v (uniform per block: 128-aligned)
    int h = (col & 2047) >> 7;    // head (uniform per block)
    int d = col & 127;
#pragma unroll
    for (int m = 0; m < 4; ++m) {
#pragma unroll
      for (int g = 0; g < 4; ++g) {
        int row = bm * 128 + wr * 64 + m * 16 + lg * 4 + g;  // token in [0,8192)
        int b = row >> 11, t = row & 2047;
        unsigned short val = f2bf(acc[m][n][g] + bv);
        size_t bhi = (size_t)(b * 16 + h);
        if (which == 0)      qb[(bhi * 2048 + t) * 128 + d] = val;
        else if (which == 1) kb[(bhi * 2048 + t) * 128 + d] = val;
        else                 vtb[(bhi * 128 + d) * 2048 + t] = val;
      }
    }
  }
}

// ---------------- Proj GEMM: fp32 output + bias ----------------
__global__ __launch_bounds__(256) void gemm_proj_kernel(const unsigned short* __restrict__ A,
                                                        const unsigned short* __restrict__ Bt,
                                                        const float* __restrict__ bias,
                                                        float* __restrict__ out) {
  __shared__ unsigned short a_lds[128 * 64];
  __shared__ unsigned short b_lds[128 * 64];
  int bm = blockIdx.x, bn = blockIdx.y;
  int tid = threadIdx.x;
  f32x4 acc[4][4];
  f32x4 zero = {0.f, 0.f, 0.f, 0.f};
#pragma unroll
  for (int m = 0; m < 4; ++m)
#pragma unroll
    for (int n = 0; n < 4; ++n) acc[m][n] = zero;

  gemm128_mainloop(A + (size_t)bm * 128 * 2048, Bt + (size_t)bn * 128 * 2048,
                   a_lds, b_lds, 2048, tid, acc);

  int wid = tid >> 6, lane = tid & 63;
  int wr = wid >> 1, wc = wid & 1, lg = lane >> 4, l15 = lane & 15;
#pragma unroll
  for (int n = 0; n < 4; ++n) {
    int col = bn * 128 + wc * 64 + n * 16 + l15;
    float bv = bias[col];
#pragma unroll
    for (int m = 0; m < 4; ++m) {
#pragma unroll
      for (int g = 0; g < 4; ++g) {
        int row = bm * 128 + wr * 64 + m * 16 + lg * 4 + g;
        out[(size_t)row * 2048 + col] = acc[m][n][g] + bv;
      }
    }
  }
}

// ---------------- Flash attention: QBLK=64 (4 waves x 16 rows), KVBLK=64, causal ----------------
__global__ __launch_bounds__(256) void attn_kernel(const unsigned short* __restrict__ qb,
                                                   const unsigned short* __restrict__ kb,
                                                   const unsigned short* __restrict__ vtb,
                                                   unsigned short* __restrict__ ob) {
  __shared__ unsigned short k_lds[64 * 128];   // 16KB, XOR-swizzled (chunk ^= row&7)
  __shared__ unsigned short vt_lds[128 * 64];  // 16KB, XOR-swizzled
  __shared__ unsigned short p_lds[4 * 16 * 64]; // 8KB, per-wave, swizzled

  int qt = blockIdx.x;   // 0..31
  int bh = blockIdx.y;   // 0..63
  int b = bh >> 4, h = bh & 15;
  int tid = threadIdx.x, wid = tid >> 6, lane = tid & 63;
  int lg = lane >> 4, l15 = lane & 15;

  const unsigned short* Q  = qb  + (size_t)bh * 2048 * 128;
  const unsigned short* K  = kb  + (size_t)bh * 2048 * 128;
  const unsigned short* Vt = vtb + (size_t)bh * 128 * 2048;

  int qrow0 = qt * 64 + wid * 16;

  // Q fragments in registers: row = l15, k-chunks of 32 over D=128
  short8 qf[4];
#pragma unroll
  for (int kc = 0; kc < 4; ++kc)
    qf[kc] = *(const short8*)(Q + (size_t)(qrow0 + l15) * 128 + kc * 32 + lg * 8);

  f32x4 o[8];
  f32x4 zero = {0.f, 0.f, 0.f, 0.f};
#pragma unroll
  for (int dt = 0; dt < 8; ++dt) o[dt] = zero;
  float m_run[4], l_run[4];
#pragma unroll
  for (int g = 0; g < 4; ++g) { m_run[g] = -1e30f; l_run[g] = 0.f; }

  const float sscale = 0.08838834764831845f * LOG2E;  // D^-0.5 * log2(e)

  for (int kt = 0; kt <= qt; ++kt) {
    __syncthreads();
    // stage K tile [64][128] with pre-swizzled global source (linear LDS dest)
#pragma unroll
    for (int it = 0; it < 4; ++it) {
      int li = it * 256 + tid;
      int r = li >> 4, c = li & 15;
      int cs = c ^ (r & 7);
      GLOAD16(K + (size_t)(kt * 64 + r) * 128 + cs * 8, (char*)k_lds + li * 16);
    }
    // stage Vt tile [128][64]
#pragma unroll
    for (int it = 0; it < 4; ++it) {
      int li = it * 256 + tid;
      int r = li >> 3, c = li & 7;
      int cs = c ^ (r & 7);
      GLOAD16(Vt + (size_t)r * 2048 + kt * 64 + cs * 8, (char*)vt_lds + li * 16);
    }
    __syncthreads();

    // S = Q K^T  (16 q-rows x 64 kv)
    f32x4 s[4];
#pragma unroll
    for (int nt = 0; nt < 4; ++nt) s[nt] = zero;
#pragma unroll
    for (int nt = 0; nt < 4; ++nt) {
#pragma unroll
      for (int kc = 0; kc < 4; ++kc) {
        int rr = nt * 16 + l15;
        int ch = (kc * 4 + lg) ^ (rr & 7);
        short8 kf = *(const short8*)((const char*)k_lds + rr * 256 + ch * 16);
        s[nt] = __builtin_amdgcn_mfma_f32_16x16x32_bf16(qf[kc], kf, s[nt], 0, 0, 0);
      }
    }

    // scale + causal mask (diagonal tile only), log2 units
    float sv[4][4];
    bool diag = (kt == qt);
#pragma unroll
    for (int nt = 0; nt < 4; ++nt) {
#pragma unroll
      for (int g = 0; g < 4; ++g) {
        float x = s[nt][g] * sscale;
        if (diag) {
          int qg = qrow0 + lg * 4 + g;
          int kg = kt * 64 + nt * 16 + l15;
          if (kg > qg) x = -1e30f;
        }
        sv[nt][g] = x;
      }
    }

    // online softmax: row stats live in the 16-lane group (xor 1,2,4,8 stays in group)
    float pmax[4];
#pragma unroll
    for (int g = 0; g < 4; ++g) {
      float v = fmaxf(fmaxf(sv[0][g], sv[1][g]), fmaxf(sv[2][g], sv[3][g]));
      v = fmaxf(v, __shfl_xor(v, 1));
      v = fmaxf(v, __shfl_xor(v, 2));
      v = fmaxf(v, __shfl_xor(v, 4));
      v = fmaxf(v, __shfl_xor(v, 8));
      pmax[g] = v;
    }
    float alpha[4];
#pragma unroll
    for (int g = 0; g < 4; ++g) {
      float mn = fmaxf(m_run[g], pmax[g]);
      alpha[g] = exp2f(m_run[g] - mn);
      m_run[g] = mn;
    }
    float rsum[4] = {0.f, 0.f, 0.f, 0.f};
    unsigned short pb[4][4];
#pragma unroll
    for (int nt = 0; nt < 4; ++nt) {
#pragma unroll
      for (int g = 0; g < 4; ++g) {
        float p = exp2f(sv[nt][g] - m_run[g]);
        rsum[g] += p;
        pb[nt][g] = f2bf(p);
      }
    }
#pragma unroll
    for (int g = 0; g < 4; ++g) {
      float v = rsum[g];
      v += __shfl_xor(v, 1);
      v += __shfl_xor(v, 2);
      v += __shfl_xor(v, 4);
      v += __shfl_xor(v, 8);
      l_run[g] = l_run[g] * alpha[g] + v;
    }

    // write P to per-wave LDS (swizzled), C-layout row = lg*4+g
    char* pw = (char*)p_lds + wid * 2048;
#pragma unroll
    for (int nt = 0; nt < 4; ++nt) {
#pragma unroll
      for (int g = 0; g < 4; ++g) {
        int r = lg * 4 + g;
        int byt = (nt * 32 + l15 * 2) ^ ((r & 7) << 4);
        *(unsigned short*)(pw + r * 128 + byt) = pb[nt][g];
      }
    }
    // rescale O
#pragma unroll
    for (int dt = 0; dt < 8; ++dt) {
#pragma unroll
      for (int g = 0; g < 4; ++g) o[dt][g] *= alpha[g];
    }
    asm volatile("s_waitcnt lgkmcnt(0)" ::: "memory");  // P writes visible before reads

    // O += P @ V   (P as A-operand rows = l15; Vt rows = d)
#pragma unroll
    for (int kc = 0; kc < 2; ++kc) {
      int rr = l15;
      int chp = (kc * 4 + lg) ^ (rr & 7);
      short8 pf = *(const short8*)(pw + rr * 128 + chp * 16);
#pragma unroll
      for (int dt = 0; dt < 8; ++dt) {
        int rv = dt * 16 + l15;
        int cv = (kc * 4 + lg) ^ (rv & 7);
        short8 vf = *(const short8*)((const char*)vt_lds + rv * 128 + cv * 16);
        o[dt] = __builtin_amdgcn_mfma_f32_16x16x32_bf16(pf, vf, o[dt], 0, 0, 0);
      }
    }
  }

  // epilogue: normalize, write attn_out [8192][2048] bf16 at [b*2048+t][h*128+d]
#pragma unroll
  for (int g = 0; g < 4; ++g) {
    float inv = 1.0f / l_run[g];
    int t = qrow0 + lg * 4 + g;
    size_t base = ((size_t)(b * 2048 + t)) * 2048 + h * 128;
#pragma unroll
    for (int dt = 0; dt < 8; ++dt)
      ob[base + dt * 16 + l15] = f2bf(o[dt][g] * inv);
  }
}

// ---------------- launch ----------------
extern "C" void kernel_launch(void* const* d_in, const int* in_sizes, int n_in,
                              void* d_out, int out_size, void* d_ws, size_t ws_size,
                              hipStream_t stream) {
  const float* x     = (const float*)d_in[0];
  const float* Wqkv  = (const float*)d_in[1];
  const float* bqkv  = (const float*)d_in[2];
  const float* Wproj = (const float*)d_in[3];
  const float* bproj = (const float*)d_in[4];
  float* out = (float*)d_out;

  // workspace layout (160 MiB total):
  // [0,32M)    x_bf16            -> reused as attn_out bf16 after qkv GEMM
  // [32M,56M)  Wqkv^T bf16 [6144][2048]
  // [56M,64M)  Wproj^T bf16 [2048][2048]
  // [64M,96M)  q  [bh][t][d] bf16
  // [96M,128M) k  [bh][t][d] bf16
  // [128M,160M) v^T [bh][d][t] bf16
  char* ws = (char*)d_ws;
  unsigned short* x_bf   = (unsigned short*)ws;
  unsigned short* wqkvt  = (unsigned short*)(ws + 33554432);
  unsigned short* wprojt = (unsigned short*)(ws + 33554432 + 25165824);
  unsigned short* qb     = (unsigned short*)(ws + 67108864);
  unsigned short* kb     = (unsigned short*)(ws + 100663296);
  unsigned short* vtb    = (unsigned short*)(ws + 134217728);

  cast_bf16_kernel<<<16384, 256, 0, stream>>>(x, x_bf);
  transpose_cast_kernel<<<dim3(192, 64), dim3(32, 8), 0, stream>>>(Wqkv, wqkvt, 2048, 6144);
  transpose_cast_kernel<<<dim3(64, 64), dim3(32, 8), 0, stream>>>(Wproj, wprojt, 2048, 2048);
  gemm_qkv_kernel<<<dim3(64, 48), 256, 0, stream>>>(x_bf, wqkvt, bqkv, qb, kb, vtb);
  attn_kernel<<<dim3(32, 64), 256, 0, stream>>>(qb, kb, vtb, x_bf /* attn_out */);
  gemm_proj_kernel<<<dim3(64, 16), 256, 0, stream>>>(x_bf, wprojt, bproj, out);
}

// Round 3
// 734.602 us; speedup vs baseline: 1.1165x; 1.1165x over previous
//
#include <hip/hip_runtime.h>
#include <hip/hip_bf16.h>
#include <stdint.h>

typedef __attribute__((ext_vector_type(8))) short short8;
typedef __attribute__((ext_vector_type(4))) float f32x4;
typedef __attribute__((ext_vector_type(16))) float f32x16;
typedef __attribute__((ext_vector_type(2))) unsigned int uint2v;

__device__ __forceinline__ unsigned short f2bf(float f) {
  union { float f; unsigned int u; } v; v.f = f;
  unsigned int r = v.u + 0x7FFFu + ((v.u >> 16) & 1u);
  return (unsigned short)(r >> 16);
}

__device__ __forceinline__ unsigned int cvtpk(float lo, float hi) {
  unsigned int r;
  asm("v_cvt_pk_bf16_f32 %0, %1, %2" : "=v"(r) : "v"(lo), "v"(hi));
  return r;
}

#define GLOAD16(gsrc, ldst)                                                                  \
  __builtin_amdgcn_global_load_lds((const __attribute__((address_space(1))) void*)(gsrc),    \
                                   (__attribute__((address_space(3))) void*)(ldst), 16, 0, 0)

// ---------------- cast x (fp32 -> bf16), 4 elems/thread ----------------
__global__ __launch_bounds__(256) void cast_bf16_kernel(const float* __restrict__ in,
                                                        unsigned short* __restrict__ out) {
  int i = blockIdx.x * 256 + threadIdx.x;
  float4 v = ((const float4*)in)[i];
  ushort4 o;
  o.x = f2bf(v.x); o.y = f2bf(v.y); o.z = f2bf(v.z); o.w = f2bf(v.w);
  ((ushort4*)out)[i] = o;
}

// ---------------- transpose + cast W: [K][N] fp32 -> [N][K] bf16 ----------------
__global__ __launch_bounds__(256) void transpose_cast_kernel(const float* __restrict__ W,
                                                             unsigned short* __restrict__ Wt,
                                                             int K, int N) {
  __shared__ float tile[32][33];
  int n0 = blockIdx.x * 32, k0 = blockIdx.y * 32;
  int tx = threadIdx.x, ty = threadIdx.y;
#pragma unroll
  for (int j = 0; j < 32; j += 8)
    tile[ty + j][tx] = W[(size_t)(k0 + ty + j) * N + n0 + tx];
  __syncthreads();
#pragma unroll
  for (int j = 0; j < 32; j += 8)
    Wt[(size_t)(n0 + ty + j) * K + k0 + tx] = f2bf(tile[tx][ty + j]);
}

// ---------------- 128x128 tile GEMM mainloop (m97 structure) ----------------
__device__ __forceinline__ void gemm128_mainloop(const unsigned short* __restrict__ Ap,
                                                 const unsigned short* __restrict__ Bp,
                                                 unsigned short* a_lds, unsigned short* b_lds,
                                                 int K, int tid, f32x4 acc[4][4]) {
  int wid = tid >> 6, lane = tid & 63;
  int wr = wid >> 1, wc = wid & 1;
  int lg = lane >> 4, l15 = lane & 15;
  for (int k0 = 0; k0 < K; k0 += 64) {
    __syncthreads();
#pragma unroll
    for (int it = 0; it < 4; ++it) {
      int li = it * 256 + tid;
      int r = li >> 3, c = li & 7;
      GLOAD16(Ap + (size_t)r * K + k0 + c * 8, (char*)a_lds + li * 16);
    }
#pragma unroll
    for (int it = 0; it < 4; ++it) {
      int li = it * 256 + tid;
      int r = li >> 3, c = li & 7;
      GLOAD16(Bp + (size_t)r * K + k0 + c * 8, (char*)b_lds + li * 16);
    }
    __syncthreads();
#pragma unroll
    for (int kc = 0; kc < 2; ++kc) {
      short8 af[4], bfv[4];
#pragma unroll
      for (int m = 0; m < 4; ++m)
        af[m] = *(const short8*)(a_lds + (wr * 64 + m * 16 + l15) * 64 + kc * 32 + lg * 8);
#pragma unroll
      for (int n = 0; n < 4; ++n)
        bfv[n] = *(const short8*)(b_lds + (wc * 64 + n * 16 + l15) * 64 + kc * 32 + lg * 8);
#pragma unroll
      for (int m = 0; m < 4; ++m)
#pragma unroll
        for (int n = 0; n < 4; ++n)
          acc[m][n] = __builtin_amdgcn_mfma_f32_16x16x32_bf16(af[m], bfv[n], acc[m][n], 0, 0, 0);
    }
  }
}

// ---------------- QKV GEMM: scatter q (pre-scaled) / k ([bh][t][d]) and v transposed ----------------
__global__ __launch_bounds__(256) void gemm_qkv_kernel(const unsigned short* __restrict__ A,
                                                       const unsigned short* __restrict__ Bt,
                                                       const float* __restrict__ bias,
                                                       unsigned short* __restrict__ qb,
                                                       unsigned short* __restrict__ kb,
                                                       unsigned short* __restrict__ vtb) {
  __shared__ unsigned short a_lds[128 * 64];
  __shared__ unsigned short b_lds[128 * 64];
  int bm = blockIdx.x, bn = blockIdx.y;
  int tid = threadIdx.x;
  f32x4 acc[4][4];
  f32x4 zero = {0.f, 0.f, 0.f, 0.f};
#pragma unroll
  for (int m = 0; m < 4; ++m)
#pragma unroll
    for (int n = 0; n < 4; ++n) acc[m][n] = zero;

  gemm128_mainloop(A + (size_t)bm * 128 * 2048, Bt + (size_t)bn * 128 * 2048,
                   a_lds, b_lds, 2048, tid, acc);

  const float QSCALE = (float)(0.08838834764831845 * 1.4426950408889634);  // D^-0.5 * log2(e)
  int wid = tid >> 6, lane = tid & 63;
  int wr = wid >> 1, wc = wid & 1, lg = lane >> 4, l15 = lane & 15;
#pragma unroll
  for (int n = 0; n < 4; ++n) {
    int col = bn * 128 + wc * 64 + n * 16 + l15;
    float bv = bias[col];
    int which = col >> 11;
    int h = (col & 2047) >> 7;
    int d = col & 127;
#pragma unroll
    for (int m = 0; m < 4; ++m) {
#pragma unroll
      for (int g = 0; g < 4; ++g) {
        int row = bm * 128 + wr * 64 + m * 16 + lg * 4 + g;
        int b = row >> 11, t = row & 2047;
        float r = acc[m][n][g] + bv;
        if (which == 0) r *= QSCALE;
        unsigned short val = f2bf(r);
        size_t bhi = (size_t)(b * 16 + h);
        if (which == 0)      qb[(bhi * 2048 + t) * 128 + d] = val;
        else if (which == 1) kb[(bhi * 2048 + t) * 128 + d] = val;
        else                 vtb[(bhi * 128 + d) * 2048 + t] = val;
      }
    }
  }
}

// ---------------- Proj GEMM: fp32 output + bias ----------------
__global__ __launch_bounds__(256) void gemm_proj_kernel(const unsigned short* __restrict__ A,
                                                        const unsigned short* __restrict__ Bt,
                                                        const float* __restrict__ bias,
                                                        float* __restrict__ out) {
  __shared__ unsigned short a_lds[128 * 64];
  __shared__ unsigned short b_lds[128 * 64];
  int bm = blockIdx.x, bn = blockIdx.y;
  int tid = threadIdx.x;
  f32x4 acc[4][4];
  f32x4 zero = {0.f, 0.f, 0.f, 0.f};
#pragma unroll
  for (int m = 0; m < 4; ++m)
#pragma unroll
    for (int n = 0; n < 4; ++n) acc[m][n] = zero;

  gemm128_mainloop(A + (size_t)bm * 128 * 2048, Bt + (size_t)bn * 128 * 2048,
                   a_lds, b_lds, 2048, tid, acc);

  int wid = tid >> 6, lane = tid & 63;
  int wr = wid >> 1, wc = wid & 1, lg = lane >> 4, l15 = lane & 15;
#pragma unroll
  for (int n = 0; n < 4; ++n) {
    int col = bn * 128 + wc * 64 + n * 16 + l15;
    float bv = bias[col];
#pragma unroll
    for (int m = 0; m < 4; ++m) {
#pragma unroll
      for (int g = 0; g < 4; ++g) {
        int row = bm * 128 + wr * 64 + m * 16 + lg * 4 + g;
        out[(size_t)row * 2048 + col] = acc[m][n][g] + bv;
      }
    }
  }
}

// ---------------- Flash attention: QBLK=128 (4 waves x 32 rows), KVBLK=64, 32x32 MFMA ----------------
// Swapped QK^T (S^T col = qrow = lane&31) -> lane-local softmax; P built in-register via
// cvt_pk_bf16 + permlane32_swap (no LDS round-trip); O kept transposed (O^T[d][q], col=qrow).
__global__ __launch_bounds__(256) void attn_kernel(const unsigned short* __restrict__ qb,
                                                   const unsigned short* __restrict__ kb,
                                                   const unsigned short* __restrict__ vtb,
                                                   unsigned short* __restrict__ ob) {
  __shared__ unsigned short k_lds[64 * 128];   // 16KB, chunk ^= row&7 swizzle (16 chunks/row)
  __shared__ unsigned short vt_lds[128 * 64];  // 16KB, chunk ^= row&7 swizzle (8 chunks/row)

  int qt = 15 - (int)blockIdx.x;  // heavy blocks first
  int bh = blockIdx.y;
  int b = bh >> 4, h = bh & 15;
  int tid = threadIdx.x, wid = tid >> 6, lane = tid & 63;
  int l31 = lane & 31, hi = lane >> 5;

  const unsigned short* Q  = qb  + (size_t)bh * 2048 * 128;
  const unsigned short* K  = kb  + (size_t)bh * 2048 * 128;
  const unsigned short* Vt = vtb + (size_t)bh * 128 * 2048;

  int qbase = qt * 128 + wid * 32;
  int qrow = qbase + l31;

  // Q fragments (B-operand): col=qrow=l31, k = kc*16 + hi*8 + j over D=128
  short8 qf[8];
#pragma unroll
  for (int kc = 0; kc < 8; ++kc)
    qf[kc] = *(const short8*)(Q + (size_t)qrow * 128 + kc * 16 + hi * 8);

  f32x16 o0 = {}, o1 = {}, o2 = {}, o3 = {};  // O^T[d = dt*32+crow][q = l31]
  float m_run = -1e30f, l_run = 0.f;

  int ktmax = 2 * qt + 1;
  for (int kt = 0; kt <= ktmax; ++kt) {
    __syncthreads();
    // stage K tile [64][128]: LDS[r][c] = K[r][c^(r&7)]
#pragma unroll
    for (int it = 0; it < 4; ++it) {
      int li = it * 256 + tid;
      int r = li >> 4, c = li & 15;
      int cs = c ^ (r & 7);
      GLOAD16(K + (size_t)(kt * 64 + r) * 128 + cs * 8, (char*)k_lds + li * 16);
    }
    // stage Vt tile [128][64]: LDS[r][c] = Vt[r][c^(r&7)]
#pragma unroll
    for (int it = 0; it < 4; ++it) {
      int li = it * 256 + tid;
      int r = li >> 3, c = li & 7;
      int cs = c ^ (r & 7);
      GLOAD16(Vt + (size_t)r * 2048 + kt * 64 + cs * 8, (char*)vt_lds + li * 16);
    }
    __syncthreads();

    bool active = (kt * 64 <= qbase + 31);  // wave-uniform
    if (!active) continue;

    // S^T = K Q^T : s[r] = S[kv = kt*64 + kvt*32 + crow(r,hi)][qrow]
    f32x16 s0v = {}, s1v = {};
#pragma unroll
    for (int kc = 0; kc < 8; ++kc) {
      int cg = kc * 2 + hi;
      int sw = l31 & 7;
      short8 kf0 = *(const short8*)((const char*)k_lds + l31 * 256 + ((cg ^ sw) * 16));
      s0v = __builtin_amdgcn_mfma_f32_32x32x16_bf16(kf0, qf[kc], s0v, 0, 0, 0);
      short8 kf1 = *(const short8*)((const char*)k_lds + (32 + l31) * 256 + ((cg ^ sw) * 16));
      s1v = __builtin_amdgcn_mfma_f32_32x32x16_bf16(kf1, qf[kc], s1v, 0, 0, 0);
    }

    // causal mask (only tiles overlapping the diagonal)
    if (kt * 64 + 63 > qbase) {
      int kvb = kt * 64 + 4 * hi;
#pragma unroll
      for (int r = 0; r < 16; ++r) {
        int kv = kvb + (r & 3) + 8 * (r >> 2);
        if (kv > qrow) s0v[r] = -1e30f;
        if (kv + 32 > qrow) s1v[r] = -1e30f;
      }
    }

    // row max (qrow is lane-local; partner lane l^32 holds the other rows)
    float tmax[16];
#pragma unroll
    for (int i = 0; i < 16; ++i) tmax[i] = fmaxf(s0v[i], s1v[i]);
#pragma unroll
    for (int st = 8; st >= 1; st >>= 1)
#pragma unroll
      for (int i = 0; i < st; ++i) tmax[i] = fmaxf(tmax[i], tmax[i + st]);
    float pmax = fmaxf(tmax[0], __shfl_xor(tmax[0], 32));

    // defer-max (T13): rescale only when max grows by > 8 (log2 units)
    if (!__all(pmax <= m_run + 8.0f)) {
      float mn = fmaxf(m_run, pmax);
      float alpha = exp2f(m_run - mn);
      m_run = mn; l_run *= alpha;
      o0 *= alpha; o1 *= alpha; o2 *= alpha; o3 *= alpha;
    }

    // P = exp2(S - m), row sum
#pragma unroll
    for (int i = 0; i < 16; ++i) {
      s0v[i] = exp2f(s0v[i] - m_run);
      s1v[i] = exp2f(s1v[i] - m_run);
    }
    float tsum[16];
#pragma unroll
    for (int i = 0; i < 16; ++i) tsum[i] = s0v[i] + s1v[i];
#pragma unroll
    for (int st = 8; st >= 1; st >>= 1)
#pragma unroll
      for (int i = 0; i < st; ++i) tsum[i] += tsum[i + st];
    float rsum = tsum[0] + __shfl_xor(tsum[0], 32);
    l_run += rsum;

    // build P fragments in-register (B-operand layout: col=qrow=l31, k=hi*8+j)
    // permlane32_swap(low, high): res0 = {low(0:31) | high(0:31)} -> word holding kv (8hi+0,8hi+1)
    //                             res1 = {low(32:63) | high(32:63)} -> word holding kv (8hi+4,8hi+5)
#define BUILD_PA(sv, base, out)                                                \
    {                                                                          \
      unsigned int a_ = cvtpk(sv[base + 0], sv[base + 1]); /* kv 4hi+0,1   */  \
      unsigned int c_ = cvtpk(sv[base + 2], sv[base + 3]); /* kv 4hi+2,3   */  \
      unsigned int b_ = cvtpk(sv[base + 4], sv[base + 5]); /* kv 8+4hi+0,1 */  \
      unsigned int d_ = cvtpk(sv[base + 6], sv[base + 7]); /* kv 8+4hi+2,3 */  \
      uint2v r0_ = __builtin_amdgcn_permlane32_swap(a_, b_, false, false);     \
      uint2v r1_ = __builtin_amdgcn_permlane32_swap(c_, d_, false, false);     \
      union { unsigned int u[4]; short8 v; } uu_;                              \
      uu_.u[0] = r0_[0]; uu_.u[1] = r1_[0]; uu_.u[2] = r0_[1]; uu_.u[3] = r1_[1]; \
      out = uu_.v;                                                             \
    }
    short8 pa0, pa1, pa2, pa3;
    BUILD_PA(s0v, 0, pa0);  // kv 0..15 of tile
    BUILD_PA(s0v, 8, pa1);  // kv 16..31
    BUILD_PA(s1v, 0, pa2);  // kv 32..47
    BUILD_PA(s1v, 8, pa3);  // kv 48..63
#undef BUILD_PA

    // O^T += Vt @ P : A = Vt[d][kv], B = P (col=qrow)
#define PV_STEP(ovar, dt)                                                              \
    {                                                                                  \
      int rv_ = dt * 32 + l31;                                                         \
      const char* vb_ = (const char*)vt_lds + rv_ * 128;                               \
      int sw_ = rv_ & 7;                                                               \
      short8 v0_ = *(const short8*)(vb_ + (((0 + hi) ^ sw_) * 16));                    \
      ovar = __builtin_amdgcn_mfma_f32_32x32x16_bf16(v0_, pa0, ovar, 0, 0, 0);         \
      short8 v1_ = *(const short8*)(vb_ + (((2 + hi) ^ sw_) * 16));                    \
      ovar = __builtin_amdgcn_mfma_f32_32x32x16_bf16(v1_, pa1, ovar, 0, 0, 0);         \
      short8 v2_ = *(const short8*)(vb_ + (((4 + hi) ^ sw_) * 16));                    \
      ovar = __builtin_amdgcn_mfma_f32_32x32x16_bf16(v2_, pa2, ovar, 0, 0, 0);         \
      short8 v3_ = *(const short8*)(vb_ + (((6 + hi) ^ sw_) * 16));                    \
      ovar = __builtin_amdgcn_mfma_f32_32x32x16_bf16(v3_, pa3, ovar, 0, 0, 0);         \
    }
    PV_STEP(o0, 0)
    PV_STEP(o1, 1)
    PV_STEP(o2, 2)
    PV_STEP(o3, 3)
#undef PV_STEP
  }

  // epilogue: normalize, write attn_out[t][h*128+d], d = dt*32 + rq*8 + 4*hi + i
  float inv = 1.0f / l_run;
  size_t orow = (size_t)(b * 2048 + qt * 128 + wid * 32 + l31);
  unsigned short* ob_p = ob + orow * 2048 + h * 128;
#define STORE_DT(ovar, dt)                                                             \
  {                                                                                    \
    _Pragma("unroll")                                                                  \
    for (int rq = 0; rq < 4; ++rq) {                                                   \
      unsigned int w0 = cvtpk(ovar[rq * 4 + 0] * inv, ovar[rq * 4 + 1] * inv);         \
      unsigned int w1 = cvtpk(ovar[rq * 4 + 2] * inv, ovar[rq * 4 + 3] * inv);         \
      uint2v st = {w0, w1};                                                            \
      *(uint2v*)(ob_p + dt * 32 + rq * 8 + 4 * hi) = st;                               \
    }                                                                                  \
  }
  STORE_DT(o0, 0)
  STORE_DT(o1, 1)
  STORE_DT(o2, 2)
  STORE_DT(o3, 3)
#undef STORE_DT
}

// ---------------- launch ----------------
extern "C" void kernel_launch(void* const* d_in, const int* in_sizes, int n_in,
                              void* d_out, int out_size, void* d_ws, size_t ws_size,
                              hipStream_t stream) {
  const float* x     = (const float*)d_in[0];
  const float* Wqkv  = (const float*)d_in[1];
  const float* bqkv  = (const float*)d_in[2];
  const float* Wproj = (const float*)d_in[3];
  const float* bproj = (const float*)d_in[4];
  float* out = (float*)d_out;

  char* ws = (char*)d_ws;
  unsigned short* x_bf   = (unsigned short*)ws;                         // 32MB, reused as attn_out
  unsigned short* wqkvt  = (unsigned short*)(ws + 33554432);            // 24MB
  unsigned short* wprojt = (unsigned short*)(ws + 33554432 + 25165824); // 8MB
  unsigned short* qb     = (unsigned short*)(ws + 67108864);            // 32MB (pre-scaled)
  unsigned short* kb     = (unsigned short*)(ws + 100663296);           // 32MB
  unsigned short* vtb    = (unsigned short*)(ws + 134217728);           // 32MB [bh][d][t]

  cast_bf16_kernel<<<16384, 256, 0, stream>>>(x, x_bf);
  transpose_cast_kernel<<<dim3(192, 64), dim3(32, 8), 0, stream>>>(Wqkv, wqkvt, 2048, 6144);
  transpose_cast_kernel<<<dim3(64, 64), dim3(32, 8), 0, stream>>>(Wproj, wprojt, 2048, 2048);
  gemm_qkv_kernel<<<dim3(64, 48), 256, 0, stream>>>(x_bf, wqkvt, bqkv, qb, kb, vtb);
  attn_kernel<<<dim3(16, 64), 256, 0, stream>>>(qb, kb, vtb, x_bf /* attn_out */);
  gemm_proj_kernel<<<dim3(64, 16), 256, 0, stream>>>(x_bf, wprojt, bproj, out);
}

// Round 4
// 630.012 us; speedup vs baseline: 1.3018x; 1.1660x over previous
//
#include <hip/hip_runtime.h>
#include <hip/hip_bf16.h>
#include <stdint.h>

typedef __attribute__((ext_vector_type(8))) short short8;
typedef __attribute__((ext_vector_type(4))) float f32x4;
typedef __attribute__((ext_vector_type(16))) float f32x16;
typedef __attribute__((ext_vector_type(2))) unsigned int uint2v;

__device__ __forceinline__ unsigned short f2bf(float f) {
  union { float f; unsigned int u; } v; v.f = f;
  unsigned int r = v.u + 0x7FFFu + ((v.u >> 16) & 1u);
  return (unsigned short)(r >> 16);
}

__device__ __forceinline__ unsigned int cvtpk(float lo, float hi) {
  unsigned int r;
  asm("v_cvt_pk_bf16_f32 %0, %1, %2" : "=v"(r) : "v"(lo), "v"(hi));
  return r;
}

#define GLOAD16(gsrc, ldst)                                                                  \
  __builtin_amdgcn_global_load_lds((const __attribute__((address_space(1))) void*)(gsrc),    \
                                   (__attribute__((address_space(3))) void*)(ldst), 16, 0, 0)

#define BAR() __builtin_amdgcn_s_barrier()
#define LGKM0() do { asm volatile("s_waitcnt lgkmcnt(0)" ::: "memory"); \
                     __builtin_amdgcn_sched_barrier(0); } while (0)
#define VMCNT6() asm volatile("s_waitcnt vmcnt(6)" ::: "memory")
#define PRIO(x) __builtin_amdgcn_s_setprio(x)

// ---------------- cast x (fp32 -> bf16), 4 elems/thread ----------------
__global__ __launch_bounds__(256) void cast_bf16_kernel(const float* __restrict__ in,
                                                        unsigned short* __restrict__ out) {
  int i = blockIdx.x * 256 + threadIdx.x;
  float4 v = ((const float4*)in)[i];
  ushort4 o;
  o.x = f2bf(v.x); o.y = f2bf(v.y); o.z = f2bf(v.z); o.w = f2bf(v.w);
  ((ushort4*)out)[i] = o;
}

// ---------------- transpose + cast W: [K][N] fp32 -> [N][K] bf16 ----------------
__global__ __launch_bounds__(256) void transpose_cast_kernel(const float* __restrict__ W,
                                                             unsigned short* __restrict__ Wt,
                                                             int K, int N) {
  __shared__ float tile[32][33];
  int n0 = blockIdx.x * 32, k0 = blockIdx.y * 32;
  int tx = threadIdx.x, ty = threadIdx.y;
#pragma unroll
  for (int j = 0; j < 32; j += 8)
    tile[ty + j][tx] = W[(size_t)(k0 + ty + j) * N + n0 + tx];
  __syncthreads();
#pragma unroll
  for (int j = 0; j < 32; j += 8)
    Wt[(size_t)(n0 + ty + j) * K + k0 + tx] = f2bf(tile[tx][ty + j]);
}

// ---------------- 256x256 8-phase GEMM mainloop (T2+T3+T4+T5) ----------------
// 512 threads = 8 waves (2 x 4). Wave tile 128x64 -> acc[8][4]. BK=64, 32 K-tiles.
// LDS: A 2x32KB + B 2x32KB = 128KB. Staged via global_load_lds w16 with
// pre-swizzled global source (chunk ^= row&7); reads use the same XOR -> 2 lanes/bank.
// Per K-tile: 4 phases; stages: P1:A1(t+1)->buf[t+1], P2:B0(t+2)->buf[t], P3:B1(t+2),
// P4:A0(t+2) + vmcnt(6). Counted vmcnt keeps 3 half-tiles (6 loads) in flight.
__device__ __forceinline__ void stage_half(const unsigned short* __restrict__ gp, int K,
                                           int kt, int half, char* lds_mat, int tid) {
#pragma unroll
  for (int it = 0; it < 2; ++it) {
    int li = half * 1024 + it * 512 + tid;  // 16B-chunk index in 256x64 tile
    int r = li >> 3, c = li & 7;
    int cs = c ^ (r & 7);
    GLOAD16(gp + (size_t)r * K + kt * 64 + cs * 8, lds_mat + li * 16);
  }
}

__device__ __forceinline__ void gemm256_mainloop(const unsigned short* __restrict__ Ap,
                                                 const unsigned short* __restrict__ Bp,
                                                 int K, int tid, char* smem,
                                                 f32x4 acc[8][4]) {
  char* sa = smem;           // A: 2 bufs x 32768 B
  char* sb = smem + 65536;   // B: 2 bufs x 32768 B
  const int KT = K >> 6;     // 32

  int wid = tid >> 6, lane = tid & 63;
  int wr = wid >> 2, wc = wid & 3;
  int lg = lane >> 4, l15 = lane & 15;
  int swz7 = l15 & 7;

  // prologue: t0 fully (oldest 8 loads), then t1: B0,B1,A0
  stage_half(Bp, K, 0, 0, sb, tid);
  stage_half(Bp, K, 0, 1, sb, tid);
  stage_half(Ap, K, 0, 0, sa, tid);
  stage_half(Ap, K, 0, 1, sa, tid);
  stage_half(Bp, K, 1, 0, sb + 32768, tid);
  stage_half(Bp, K, 1, 1, sb + 32768, tid);
  stage_half(Ap, K, 1, 0, sa + 32768, tid);
  VMCNT6();  // forces t0's 8 loads (t1's 6 may float)
  BAR();

#define LDA(ab, m, kc) \
  (*(const short8*)((ab) + (size_t)((wr * 128 + (m) * 16 + l15) * 64 + ((((kc) * 4 + lg) ^ swz7) * 8))))
#define LDB(bb, n, kc) \
  (*(const short8*)((bb) + (size_t)((wc * 64 + (n) * 16 + l15) * 64 + ((((kc) * 4 + lg) ^ swz7) * 8))))

  for (int t = 0; t < KT; ++t) {
    int p = t & 1, pn = p ^ 1;
    const unsigned short* ab = (const unsigned short*)(sa + p * 32768);
    const unsigned short* bb = (const unsigned short*)(sb + p * 32768);
    int kt1 = (t + 1 < KT) ? t + 1 : KT - 1;
    int kt2 = (t + 2 < KT) ? t + 2 : KT - 1;

    short8 bq[4][2], aq[4][2];
    // ---- P1: read B(all) + A(m0-3); stage A1(t+1); Q1 = m0-3 x n0-1 ----
#pragma unroll
    for (int n = 0; n < 4; ++n) { bq[n][0] = LDB(bb, n, 0); bq[n][1] = LDB(bb, n, 1); }
#pragma unroll
    for (int m = 0; m < 4; ++m) { aq[m][0] = LDA(ab, m, 0); aq[m][1] = LDA(ab, m, 1); }
    stage_half(Ap, K, kt1, 1, sa + pn * 32768, tid);
    BAR();
    LGKM0();
    PRIO(1);
#pragma unroll
    for (int kc = 0; kc < 2; ++kc)
#pragma unroll
      for (int m = 0; m < 4; ++m)
#pragma unroll
        for (int n = 0; n < 2; ++n)
          acc[m][n] = __builtin_amdgcn_mfma_f32_16x16x32_bf16(aq[m][kc], bq[n][kc], acc[m][n], 0, 0, 0);
    PRIO(0);
    BAR();

    // ---- P2: stage B0(t+2); Q2 = m0-3 x n2-3 ----
    stage_half(Bp, K, kt2, 0, sb + p * 32768, tid);
    BAR();
    PRIO(1);
#pragma unroll
    for (int kc = 0; kc < 2; ++kc)
#pragma unroll
      for (int m = 0; m < 4; ++m)
#pragma unroll
        for (int n = 2; n < 4; ++n)
          acc[m][n] = __builtin_amdgcn_mfma_f32_16x16x32_bf16(aq[m][kc], bq[n][kc], acc[m][n], 0, 0, 0);
    PRIO(0);
    BAR();

    // ---- P3: read A(m4-7); stage B1(t+2); Q3 = m4-7 x n2-3 ----
#pragma unroll
    for (int m = 0; m < 4; ++m) { aq[m][0] = LDA(ab, m + 4, 0); aq[m][1] = LDA(ab, m + 4, 1); }
    stage_half(Bp, K, kt2, 1, sb + p * 32768, tid);
    BAR();
    LGKM0();
    PRIO(1);
#pragma unroll
    for (int kc = 0; kc < 2; ++kc)
#pragma unroll
      for (int m = 0; m < 4; ++m)
#pragma unroll
        for (int n = 2; n < 4; ++n)
          acc[m + 4][n] = __builtin_amdgcn_mfma_f32_16x16x32_bf16(aq[m][kc], bq[n][kc], acc[m + 4][n], 0, 0, 0);
    PRIO(0);
    BAR();

    // ---- P4: stage A0(t+2); Q4 = m4-7 x n0-1; vmcnt(6) ----
    stage_half(Ap, K, kt2, 0, sa + p * 32768, tid);
    BAR();
    PRIO(1);
#pragma unroll
    for (int kc = 0; kc < 2; ++kc)
#pragma unroll
      for (int m = 0; m < 4; ++m)
#pragma unroll
        for (int n = 0; n < 2; ++n)
          acc[m + 4][n] = __builtin_amdgcn_mfma_f32_16x16x32_bf16(aq[m][kc], bq[n][kc], acc[m + 4][n], 0, 0, 0);
    PRIO(0);
    VMCNT6();
    BAR();
  }
#undef LDA
#undef LDB
}

// ---------------- QKV GEMM 256^2: scatter q (pre-scaled) / k / v^T ----------------
__global__ __launch_bounds__(512, 2) void gemm_qkv256_kernel(const unsigned short* __restrict__ A,
                                                             const unsigned short* __restrict__ Bt,
                                                             const float* __restrict__ bias,
                                                             unsigned short* __restrict__ qb,
                                                             unsigned short* __restrict__ kb,
                                                             unsigned short* __restrict__ vtb) {
  extern __shared__ char smem[];
  int nwg = gridDim.x, wg = blockIdx.x;
  int qx = nwg >> 3;
  int swz = (wg & 7) * qx + (wg >> 3);
  int bm = swz & 31, bn = swz >> 5;  // M/256 = 32
  int tid = threadIdx.x;

  f32x4 acc[8][4];
  f32x4 zero = {0.f, 0.f, 0.f, 0.f};
#pragma unroll
  for (int m = 0; m < 8; ++m)
#pragma unroll
    for (int n = 0; n < 4; ++n) acc[m][n] = zero;

  gemm256_mainloop(A + (size_t)bm * 256 * 2048, Bt + (size_t)bn * 256 * 2048, 2048, tid, smem, acc);

  const float QSCALE = (float)(0.08838834764831845 * 1.4426950408889634);  // D^-0.5 * log2(e)
  int wid = tid >> 6, lane = tid & 63;
  int wr = wid >> 2, wc = wid & 3, lg = lane >> 4, l15 = lane & 15;
#pragma unroll
  for (int n = 0; n < 4; ++n) {
    int col = bn * 256 + wc * 64 + n * 16 + l15;  // [0,6144)
    float bv = bias[col];
    int which = col >> 11;
    int h = (col & 2047) >> 7;
    int d = col & 127;
#pragma unroll
    for (int m = 0; m < 8; ++m) {
#pragma unroll
      for (int g = 0; g < 4; ++g) {
        int row = bm * 256 + wr * 128 + m * 16 + lg * 4 + g;  // [0,8192)
        int b = row >> 11, t = row & 2047;
        float r = acc[m][n][g] + bv;
        if (which == 0) r *= QSCALE;
        unsigned short val = f2bf(r);
        size_t bhi = (size_t)(b * 16 + h);
        if (which == 0)      qb[(bhi * 2048 + t) * 128 + d] = val;
        else if (which == 1) kb[(bhi * 2048 + t) * 128 + d] = val;
        else                 vtb[(bhi * 128 + d) * 2048 + t] = val;
      }
    }
  }
}

// ---------------- Proj GEMM 256^2: fp32 output + bias ----------------
__global__ __launch_bounds__(512, 2) void gemm_proj256_kernel(const unsigned short* __restrict__ A,
                                                              const unsigned short* __restrict__ Bt,
                                                              const float* __restrict__ bias,
                                                              float* __restrict__ out) {
  extern __shared__ char smem[];
  int nwg = gridDim.x, wg = blockIdx.x;
  int qx = nwg >> 3;
  int swz = (wg & 7) * qx + (wg >> 3);
  int bm = swz & 31, bn = swz >> 5;
  int tid = threadIdx.x;

  f32x4 acc[8][4];
  f32x4 zero = {0.f, 0.f, 0.f, 0.f};
#pragma unroll
  for (int m = 0; m < 8; ++m)
#pragma unroll
    for (int n = 0; n < 4; ++n) acc[m][n] = zero;

  gemm256_mainloop(A + (size_t)bm * 256 * 2048, Bt + (size_t)bn * 256 * 2048, 2048, tid, smem, acc);

  int wid = tid >> 6, lane = tid & 63;
  int wr = wid >> 2, wc = wid & 3, lg = lane >> 4, l15 = lane & 15;
#pragma unroll
  for (int n = 0; n < 4; ++n) {
    int col = bn * 256 + wc * 64 + n * 16 + l15;
    float bv = bias[col];
#pragma unroll
    for (int m = 0; m < 8; ++m) {
#pragma unroll
      for (int g = 0; g < 4; ++g) {
        int row = bm * 256 + wr * 128 + m * 16 + lg * 4 + g;
        out[(size_t)row * 2048 + col] = acc[m][n][g] + bv;
      }
    }
  }
}

// ---------------- Flash attention: QBLK=128 (4 waves x 32 rows), KVBLK=64, 32x32 MFMA ----------------
__global__ __launch_bounds__(256) void attn_kernel(const unsigned short* __restrict__ qb,
                                                   const unsigned short* __restrict__ kb,
                                                   const unsigned short* __restrict__ vtb,
                                                   unsigned short* __restrict__ ob) {
  __shared__ unsigned short k_lds[64 * 128];   // 16KB, chunk ^= row&7 swizzle
  __shared__ unsigned short vt_lds[128 * 64];  // 16KB, chunk ^= row&7 swizzle

  int qt = 15 - (int)blockIdx.x;  // heavy blocks first
  int bh = blockIdx.y;
  int b = bh >> 4, h = bh & 15;
  int tid = threadIdx.x, wid = tid >> 6, lane = tid & 63;
  int l31 = lane & 31, hi = lane >> 5;

  const unsigned short* Q  = qb  + (size_t)bh * 2048 * 128;
  const unsigned short* K  = kb  + (size_t)bh * 2048 * 128;
  const unsigned short* Vt = vtb + (size_t)bh * 128 * 2048;

  int qbase = qt * 128 + wid * 32;
  int qrow = qbase + l31;

  short8 qf[8];
#pragma unroll
  for (int kc = 0; kc < 8; ++kc)
    qf[kc] = *(const short8*)(Q + (size_t)qrow * 128 + kc * 16 + hi * 8);

  f32x16 o0 = {}, o1 = {}, o2 = {}, o3 = {};  // O^T[d][q=l31]
  float m_run = -1e30f, l_run = 0.f;

  int ktmax = 2 * qt + 1;
  for (int kt = 0; kt <= ktmax; ++kt) {
    __syncthreads();
#pragma unroll
    for (int it = 0; it < 4; ++it) {
      int li = it * 256 + tid;
      int r = li >> 4, c = li & 15;
      int cs = c ^ (r & 7);
      GLOAD16(K + (size_t)(kt * 64 + r) * 128 + cs * 8, (char*)k_lds + li * 16);
    }
#pragma unroll
    for (int it = 0; it < 4; ++it) {
      int li = it * 256 + tid;
      int r = li >> 3, c = li & 7;
      int cs = c ^ (r & 7);
      GLOAD16(Vt + (size_t)r * 2048 + kt * 64 + cs * 8, (char*)vt_lds + li * 16);
    }
    __syncthreads();

    bool active = (kt * 64 <= qbase + 31);
    if (!active) continue;

    f32x16 s0v = {}, s1v = {};
#pragma unroll
    for (int kc = 0; kc < 8; ++kc) {
      int cg = kc * 2 + hi;
      int sw = l31 & 7;
      short8 kf0 = *(const short8*)((const char*)k_lds + l31 * 256 + ((cg ^ sw) * 16));
      s0v = __builtin_amdgcn_mfma_f32_32x32x16_bf16(kf0, qf[kc], s0v, 0, 0, 0);
      short8 kf1 = *(const short8*)((const char*)k_lds + (32 + l31) * 256 + ((cg ^ sw) * 16));
      s1v = __builtin_amdgcn_mfma_f32_32x32x16_bf16(kf1, qf[kc], s1v, 0, 0, 0);
    }

    if (kt * 64 + 63 > qbase) {
      int kvb = kt * 64 + 4 * hi;
#pragma unroll
      for (int r = 0; r < 16; ++r) {
        int kv = kvb + (r & 3) + 8 * (r >> 2);
        if (kv > qrow) s0v[r] = -1e30f;
        if (kv + 32 > qrow) s1v[r] = -1e30f;
      }
    }

    float tmax[16];
#pragma unroll
    for (int i = 0; i < 16; ++i) tmax[i] = fmaxf(s0v[i], s1v[i]);
#pragma unroll
    for (int st = 8; st >= 1; st >>= 1)
#pragma unroll
      for (int i = 0; i < st; ++i) tmax[i] = fmaxf(tmax[i], tmax[i + st]);
    float pmax = fmaxf(tmax[0], __shfl_xor(tmax[0], 32));

    if (!__all(pmax <= m_run + 8.0f)) {
      float mn = fmaxf(m_run, pmax);
      float alpha = exp2f(m_run - mn);
      m_run = mn; l_run *= alpha;
      o0 *= alpha; o1 *= alpha; o2 *= alpha; o3 *= alpha;
    }

#pragma unroll
    for (int i = 0; i < 16; ++i) {
      s0v[i] = exp2f(s0v[i] - m_run);
      s1v[i] = exp2f(s1v[i] - m_run);
    }
    float tsum[16];
#pragma unroll
    for (int i = 0; i < 16; ++i) tsum[i] = s0v[i] + s1v[i];
#pragma unroll
    for (int st = 8; st >= 1; st >>= 1)
#pragma unroll
      for (int i = 0; i < st; ++i) tsum[i] += tsum[i + st];
    float rsum = tsum[0] + __shfl_xor(tsum[0], 32);
    l_run += rsum;

#define BUILD_PA(sv, base, out)                                                \
    {                                                                          \
      unsigned int a_ = cvtpk(sv[base + 0], sv[base + 1]);                     \
      unsigned int c_ = cvtpk(sv[base + 2], sv[base + 3]);                     \
      unsigned int b_ = cvtpk(sv[base + 4], sv[base + 5]);                     \
      unsigned int d_ = cvtpk(sv[base + 6], sv[base + 7]);                     \
      uint2v r0_ = __builtin_amdgcn_permlane32_swap(a_, b_, false, false);     \
      uint2v r1_ = __builtin_amdgcn_permlane32_swap(c_, d_, false, false);     \
      union { unsigned int u[4]; short8 v; } uu_;                              \
      uu_.u[0] = r0_[0]; uu_.u[1] = r1_[0]; uu_.u[2] = r0_[1]; uu_.u[3] = r1_[1]; \
      out = uu_.v;                                                             \
    }
    short8 pa0, pa1, pa2, pa3;
    BUILD_PA(s0v, 0, pa0);
    BUILD_PA(s0v, 8, pa1);
    BUILD_PA(s1v, 0, pa2);
    BUILD_PA(s1v, 8, pa3);
#undef BUILD_PA

#define PV_STEP(ovar, dt)                                                              \
    {                                                                                  \
      int rv_ = dt * 32 + l31;                                                         \
      const char* vb_ = (const char*)vt_lds + rv_ * 128;                               \
      int sw_ = rv_ & 7;                                                               \
      short8 v0_ = *(const short8*)(vb_ + (((0 + hi) ^ sw_) * 16));                    \
      ovar = __builtin_amdgcn_mfma_f32_32x32x16_bf16(v0_, pa0, ovar, 0, 0, 0);         \
      short8 v1_ = *(const short8*)(vb_ + (((2 + hi) ^ sw_) * 16));                    \
      ovar = __builtin_amdgcn_mfma_f32_32x32x16_bf16(v1_, pa1, ovar, 0, 0, 0);         \
      short8 v2_ = *(const short8*)(vb_ + (((4 + hi) ^ sw_) * 16));                    \
      ovar = __builtin_amdgcn_mfma_f32_32x32x16_bf16(v2_, pa2, ovar, 0, 0, 0);         \
      short8 v3_ = *(const short8*)(vb_ + (((6 + hi) ^ sw_) * 16));                    \
      ovar = __builtin_amdgcn_mfma_f32_32x32x16_bf16(v3_, pa3, ovar, 0, 0, 0);         \
    }
    PV_STEP(o0, 0)
    PV_STEP(o1, 1)
    PV_STEP(o2, 2)
    PV_STEP(o3, 3)
#undef PV_STEP
  }

  float inv = 1.0f / l_run;
  size_t orow = (size_t)(b * 2048 + qt * 128 + wid * 32 + l31);
  unsigned short* ob_p = ob + orow * 2048 + h * 128;
#define STORE_DT(ovar, dt)                                                             \
  {                                                                                    \
    _Pragma("unroll")                                                                  \
    for (int rq = 0; rq < 4; ++rq) {                                                   \
      unsigned int w0 = cvtpk(ovar[rq * 4 + 0] * inv, ovar[rq * 4 + 1] * inv);         \
      unsigned int w1 = cvtpk(ovar[rq * 4 + 2] * inv, ovar[rq * 4 + 3] * inv);         \
      uint2v st = {w0, w1};                                                            \
      *(uint2v*)(ob_p + dt * 32 + rq * 8 + 4 * hi) = st;                               \
    }                                                                                  \
  }
  STORE_DT(o0, 0)
  STORE_DT(o1, 1)
  STORE_DT(o2, 2)
  STORE_DT(o3, 3)
#undef STORE_DT
}

// ---------------- launch ----------------
extern "C" void kernel_launch(void* const* d_in, const int* in_sizes, int n_in,
                              void* d_out, int out_size, void* d_ws, size_t ws_size,
                              hipStream_t stream) {
  const float* x     = (const float*)d_in[0];
  const float* Wqkv  = (const float*)d_in[1];
  const float* bqkv  = (const float*)d_in[2];
  const float* Wproj = (const float*)d_in[3];
  const float* bproj = (const float*)d_in[4];
  float* out = (float*)d_out;

  char* ws = (char*)d_ws;
  unsigned short* x_bf   = (unsigned short*)ws;                         // 32MB, reused as attn_out
  unsigned short* wqkvt  = (unsigned short*)(ws + 33554432);            // 24MB
  unsigned short* wprojt = (unsigned short*)(ws + 33554432 + 25165824); // 8MB
  unsigned short* qb     = (unsigned short*)(ws + 67108864);            // 32MB (pre-scaled)
  unsigned short* kb     = (unsigned short*)(ws + 100663296);           // 32MB
  unsigned short* vtb    = (unsigned short*)(ws + 134217728);           // 32MB [bh][d][t]

  hipFuncSetAttribute((const void*)gemm_qkv256_kernel,
                      hipFuncAttributeMaxDynamicSharedMemorySize, 131072);
  hipFuncSetAttribute((const void*)gemm_proj256_kernel,
                      hipFuncAttributeMaxDynamicSharedMemorySize, 131072);

  cast_bf16_kernel<<<16384, 256, 0, stream>>>(x, x_bf);
  transpose_cast_kernel<<<dim3(192, 64), dim3(32, 8), 0, stream>>>(Wqkv, wqkvt, 2048, 6144);
  transpose_cast_kernel<<<dim3(64, 64), dim3(32, 8), 0, stream>>>(Wproj, wprojt, 2048, 2048);
  gemm_qkv256_kernel<<<768, 512, 131072, stream>>>(x_bf, wqkvt, bqkv, qb, kb, vtb);
  attn_kernel<<<dim3(16, 64), 256, 0, stream>>>(qb, kb, vtb, x_bf /* attn_out */);
  gemm_proj256_kernel<<<256, 512, 131072, stream>>>(x_bf, wprojt, bproj, out);
}

// Round 6
// 528.799 us; speedup vs baseline: 1.5510x; 1.1914x over previous
//
#include <hip/hip_runtime.h>
#include <hip/hip_bf16.h>
#include <stdint.h>

typedef __attribute__((ext_vector_type(8))) short short8;
typedef __attribute__((ext_vector_type(4))) float f32x4;
typedef __attribute__((ext_vector_type(16))) float f32x16;
typedef __attribute__((ext_vector_type(2))) unsigned int uint2v;

__device__ __forceinline__ unsigned short f2bf(float f) {
  union { float f; unsigned int u; } v; v.f = f;
  unsigned int r = v.u + 0x7FFFu + ((v.u >> 16) & 1u);
  return (unsigned short)(r >> 16);
}

__device__ __forceinline__ unsigned int cvtpk(float lo, float hi) {
  unsigned int r;
  asm("v_cvt_pk_bf16_f32 %0, %1, %2" : "=v"(r) : "v"(lo), "v"(hi));
  return r;
}

#define GLOAD16(gsrc, ldst)                                                                  \
  __builtin_amdgcn_global_load_lds((const __attribute__((address_space(1))) void*)(gsrc),    \
                                   (__attribute__((address_space(3))) void*)(ldst), 16, 0, 0)

#define BAR() __builtin_amdgcn_s_barrier()
#define LGKM0() do { asm volatile("s_waitcnt lgkmcnt(0)" ::: "memory"); \
                     __builtin_amdgcn_sched_barrier(0); } while (0)
#define VMCNT0() asm volatile("s_waitcnt vmcnt(0)" ::: "memory")
#define VMCNT6() asm volatile("s_waitcnt vmcnt(6)" ::: "memory")
#define PRIO(x) __builtin_amdgcn_s_setprio(x)

// ---------------- cast x (fp32 -> bf16), 4 elems/thread ----------------
__global__ __launch_bounds__(256) void cast_bf16_kernel(const float* __restrict__ in,
                                                        unsigned short* __restrict__ out) {
  int i = blockIdx.x * 256 + threadIdx.x;
  float4 v = ((const float4*)in)[i];
  ushort4 o;
  o.x = f2bf(v.x); o.y = f2bf(v.y); o.z = f2bf(v.z); o.w = f2bf(v.w);
  ((ushort4*)out)[i] = o;
}

// ---------------- transpose + cast W: [K][N] fp32 -> [N][K] bf16 ----------------
__global__ __launch_bounds__(256) void transpose_cast_kernel(const float* __restrict__ W,
                                                             unsigned short* __restrict__ Wt,
                                                             int K, int N) {
  __shared__ float tile[32][33];
  int n0 = blockIdx.x * 32, k0 = blockIdx.y * 32;
  int tx = threadIdx.x, ty = threadIdx.y;
#pragma unroll
  for (int j = 0; j < 32; j += 8)
    tile[ty + j][tx] = W[(size_t)(k0 + ty + j) * N + n0 + tx];
  __syncthreads();
#pragma unroll
  for (int j = 0; j < 32; j += 8)
    Wt[(size_t)(n0 + ty + j) * K + k0 + tx] = f2bf(tile[tx][ty + j]);
}

// ---------------- 256x256 8-phase GEMM mainloop (T2+T3+T4+T5) ----------------
__device__ __forceinline__ void stage_half(const unsigned short* __restrict__ gp, int K,
                                           int kt, int half, char* lds_mat, int tid) {
#pragma unroll
  for (int it = 0; it < 2; ++it) {
    int li = half * 1024 + it * 512 + tid;  // 16B-chunk index in 256x64 tile
    int r = li >> 3, c = li & 7;
    int cs = c ^ (r & 7);
    GLOAD16(gp + (size_t)r * K + kt * 64 + cs * 8, lds_mat + li * 16);
  }
}

__device__ __forceinline__ void gemm256_mainloop(const unsigned short* __restrict__ Ap,
                                                 const unsigned short* __restrict__ Bp,
                                                 int K, int tid, char* smem,
                                                 f32x4 acc[8][4]) {
  char* sa = smem;           // A: 2 bufs x 32768 B
  char* sb = smem + 65536;   // B: 2 bufs x 32768 B
  const int KT = K >> 6;     // 32

  int wid = tid >> 6, lane = tid & 63;
  int wr = wid >> 2, wc = wid & 3;
  int lg = lane >> 4, l15 = lane & 15;
  int swz7 = l15 & 7;

  // prologue: t0 fully (oldest 8 loads), then t1: B0,B1,A0
  stage_half(Bp, K, 0, 0, sb, tid);
  stage_half(Bp, K, 0, 1, sb, tid);
  stage_half(Ap, K, 0, 0, sa, tid);
  stage_half(Ap, K, 0, 1, sa, tid);
  stage_half(Bp, K, 1, 0, sb + 32768, tid);
  stage_half(Bp, K, 1, 1, sb + 32768, tid);
  stage_half(Ap, K, 1, 0, sa + 32768, tid);
  VMCNT6();  // forces t0's 8 loads (t1's 6 may float)
  BAR();

#define LDA(ab, m, kc) \
  (*(const short8*)((ab) + (size_t)((wr * 128 + (m) * 16 + l15) * 64 + ((((kc) * 4 + lg) ^ swz7) * 8))))
#define LDB(bb, n, kc) \
  (*(const short8*)((bb) + (size_t)((wc * 64 + (n) * 16 + l15) * 64 + ((((kc) * 4 + lg) ^ swz7) * 8))))

  for (int t = 0; t < KT; ++t) {
    int p = t & 1, pn = p ^ 1;
    const unsigned short* ab = (const unsigned short*)(sa + p * 32768);
    const unsigned short* bb = (const unsigned short*)(sb + p * 32768);
    int kt1 = (t + 1 < KT) ? t + 1 : KT - 1;
    int kt2 = (t + 2 < KT) ? t + 2 : KT - 1;

    short8 bq[4][2], aq[4][2];
    // ---- P1: read B(all) + A(m0-3); stage A1(t+1); Q1 = m0-3 x n0-1 ----
#pragma unroll
    for (int n = 0; n < 4; ++n) { bq[n][0] = LDB(bb, n, 0); bq[n][1] = LDB(bb, n, 1); }
#pragma unroll
    for (int m = 0; m < 4; ++m) { aq[m][0] = LDA(ab, m, 0); aq[m][1] = LDA(ab, m, 1); }
    stage_half(Ap, K, kt1, 1, sa + pn * 32768, tid);
    BAR();
    LGKM0();
    PRIO(1);
#pragma unroll
    for (int kc = 0; kc < 2; ++kc)
#pragma unroll
      for (int m = 0; m < 4; ++m)
#pragma unroll
        for (int n = 0; n < 2; ++n)
          acc[m][n] = __builtin_amdgcn_mfma_f32_16x16x32_bf16(aq[m][kc], bq[n][kc], acc[m][n], 0, 0, 0);
    PRIO(0);
    BAR();

    // ---- P2: stage B0(t+2); Q2 = m0-3 x n2-3 ----
    stage_half(Bp, K, kt2, 0, sb + p * 32768, tid);
    BAR();
    PRIO(1);
#pragma unroll
    for (int kc = 0; kc < 2; ++kc)
#pragma unroll
      for (int m = 0; m < 4; ++m)
#pragma unroll
        for (int n = 2; n < 4; ++n)
          acc[m][n] = __builtin_amdgcn_mfma_f32_16x16x32_bf16(aq[m][kc], bq[n][kc], acc[m][n], 0, 0, 0);
    PRIO(0);
    BAR();

    // ---- P3: read A(m4-7); stage B1(t+2); Q3 = m4-7 x n2-3 ----
#pragma unroll
    for (int m = 0; m < 4; ++m) { aq[m][0] = LDA(ab, m + 4, 0); aq[m][1] = LDA(ab, m + 4, 1); }
    stage_half(Bp, K, kt2, 1, sb + p * 32768, tid);
    BAR();
    LGKM0();
    PRIO(1);
#pragma unroll
    for (int kc = 0; kc < 2; ++kc)
#pragma unroll
      for (int m = 0; m < 4; ++m)
#pragma unroll
        for (int n = 2; n < 4; ++n)
          acc[m + 4][n] = __builtin_amdgcn_mfma_f32_16x16x32_bf16(aq[m][kc], bq[n][kc], acc[m + 4][n], 0, 0, 0);
    PRIO(0);
    BAR();

    // ---- P4: stage A0(t+2); Q4 = m4-7 x n0-1; vmcnt(6) ----
    stage_half(Ap, K, kt2, 0, sa + p * 32768, tid);
    BAR();
    PRIO(1);
#pragma unroll
    for (int kc = 0; kc < 2; ++kc)
#pragma unroll
      for (int m = 0; m < 4; ++m)
#pragma unroll
        for (int n = 0; n < 2; ++n)
          acc[m + 4][n] = __builtin_amdgcn_mfma_f32_16x16x32_bf16(aq[m][kc], bq[n][kc], acc[m + 4][n], 0, 0, 0);
    PRIO(0);
    VMCNT6();
    BAR();
  }
#undef LDA
#undef LDB
}

// ---------------- QKV GEMM 256^2: scatter q (pre-scaled) / k / v^T ----------------
__global__ __launch_bounds__(512, 2) void gemm_qkv256_kernel(const unsigned short* __restrict__ A,
                                                             const unsigned short* __restrict__ Bt,
                                                             const float* __restrict__ bias,
                                                             unsigned short* __restrict__ qb,
                                                             unsigned short* __restrict__ kb,
                                                             unsigned short* __restrict__ vtb) {
  extern __shared__ char smem[];
  int nwg = gridDim.x, wg = blockIdx.x;
  int qx = nwg >> 3;
  int swz = (wg & 7) * qx + (wg >> 3);
  int bm = swz & 31, bn = swz >> 5;  // M/256 = 32
  int tid = threadIdx.x;

  f32x4 acc[8][4];
  f32x4 zero = {0.f, 0.f, 0.f, 0.f};
#pragma unroll
  for (int m = 0; m < 8; ++m)
#pragma unroll
    for (int n = 0; n < 4; ++n) acc[m][n] = zero;

  gemm256_mainloop(A + (size_t)bm * 256 * 2048, Bt + (size_t)bn * 256 * 2048, 2048, tid, smem, acc);

  const float QSCALE = (float)(0.08838834764831845 * 1.4426950408889634);  // D^-0.5 * log2(e)
  int wid = tid >> 6, lane = tid & 63;
  int wr = wid >> 2, wc = wid & 3, lg = lane >> 4, l15 = lane & 15;
#pragma unroll
  for (int n = 0; n < 4; ++n) {
    int col = bn * 256 + wc * 64 + n * 16 + l15;  // [0,6144)
    float bv = bias[col];
    int which = col >> 11;
    int h = (col & 2047) >> 7;
    int d = col & 127;
#pragma unroll
    for (int m = 0; m < 8; ++m) {
#pragma unroll
      for (int g = 0; g < 4; ++g) {
        int row = bm * 256 + wr * 128 + m * 16 + lg * 4 + g;  // [0,8192)
        int b = row >> 11, t = row & 2047;
        float r = acc[m][n][g] + bv;
        if (which == 0) r *= QSCALE;
        unsigned short val = f2bf(r);
        size_t bhi = (size_t)(b * 16 + h);
        if (which == 0)      qb[(bhi * 2048 + t) * 128 + d] = val;
        else if (which == 1) kb[(bhi * 2048 + t) * 128 + d] = val;
        else                 vtb[(bhi * 128 + d) * 2048 + t] = val;
      }
    }
  }
}

// ---------------- Proj GEMM 256^2: fp32 output + bias ----------------
__global__ __launch_bounds__(512, 2) void gemm_proj256_kernel(const unsigned short* __restrict__ A,
                                                              const unsigned short* __restrict__ Bt,
                                                              const float* __restrict__ bias,
                                                              float* __restrict__ out) {
  extern __shared__ char smem[];
  int nwg = gridDim.x, wg = blockIdx.x;
  int qx = nwg >> 3;
  int swz = (wg & 7) * qx + (wg >> 3);
  int bm = swz & 31, bn = swz >> 5;
  int tid = threadIdx.x;

  f32x4 acc[8][4];
  f32x4 zero = {0.f, 0.f, 0.f, 0.f};
#pragma unroll
  for (int m = 0; m < 8; ++m)
#pragma unroll
    for (int n = 0; n < 4; ++n) acc[m][n] = zero;

  gemm256_mainloop(A + (size_t)bm * 256 * 2048, Bt + (size_t)bn * 256 * 2048, 2048, tid, smem, acc);

  int wid = tid >> 6, lane = tid & 63;
  int wr = wid >> 2, wc = wid & 3, lg = lane >> 4, l15 = lane & 15;
#pragma unroll
  for (int n = 0; n < 4; ++n) {
    int col = bn * 256 + wc * 64 + n * 16 + l15;
    float bv = bias[col];
#pragma unroll
    for (int m = 0; m < 8; ++m) {
#pragma unroll
      for (int g = 0; g < 4; ++g) {
        int row = bm * 256 + wr * 128 + m * 16 + lg * 4 + g;
        out[(size_t)row * 2048 + col] = acc[m][n][g] + bv;
      }
    }
  }
}

// ---------------- Flash attention: paired q-tiles, double-buffered K/V, 2-phase pipeline ----------------
// Block (i, bh) processes q-tiles {15-i, i}: exactly 34 tile-iterations per block ->
// 512 uniform blocks, 2/CU, all co-resident. Per tile: stage(next) -> compute(cur) ->
// vmcnt(0)+bar (latency hidden under compute). 32x32 swapped-operand MFMA, in-register
// softmax (cvt_pk + permlane32_swap), O kept transposed.
__global__ __launch_bounds__(256) void attn_kernel(const unsigned short* __restrict__ qb,
                                                   const unsigned short* __restrict__ kb,
                                                   const unsigned short* __restrict__ vtb,
                                                   unsigned short* __restrict__ ob) {
  extern __shared__ char asmem[];
  int pairi = blockIdx.x;  // 0..7
  int bh = blockIdx.y;
  int b = bh >> 4, h = bh & 15;
  int tid = threadIdx.x, wid = tid >> 6, lane = tid & 63;
  int l31 = lane & 31, hi = lane >> 5;

  const unsigned short* Q  = qb  + (size_t)bh * 2048 * 128;
  const unsigned short* K  = kb  + (size_t)bh * 2048 * 128;
  const unsigned short* Vt = vtb + (size_t)bh * 128 * 2048;

#pragma unroll 1
  for (int pass = 0; pass < 2; ++pass) {
    int qt = pass == 0 ? (15 - pairi) : pairi;
    int NT = 2 * qt + 2;
    int qbase = qt * 128 + wid * 32;
    int qrow = qbase + l31;

    short8 qf[8];
#pragma unroll
    for (int kc = 0; kc < 8; ++kc)
      qf[kc] = *(const short8*)(Q + (size_t)qrow * 128 + kc * 16 + hi * 8);

    f32x16 o0 = {}, o1 = {}, o2 = {}, o3 = {};  // O^T[d][q=l31]
    float m_run = -1e30f, l_run = 0.f;

    // prologue: stage tile 0 into buf0
    {
      char* kb_ = asmem;
#pragma unroll
      for (int it = 0; it < 4; ++it) {
        int li = it * 256 + tid;
        int r = li >> 4, c = li & 15;
        GLOAD16(K + (size_t)r * 128 + (c ^ (r & 7)) * 8, kb_ + li * 16);
      }
#pragma unroll
      for (int it = 0; it < 4; ++it) {
        int li = it * 256 + tid;
        int r = li >> 3, c = li & 7;
        GLOAD16(Vt + (size_t)r * 2048 + (c ^ (r & 7)) * 8, kb_ + 16384 + li * 16);
      }
    }
    VMCNT0();
    BAR();

#pragma unroll 1
    for (int kt = 0; kt < NT; ++kt) {
      char* cb = asmem + ((kt & 1) << 15);
      // stage next tile into the other buffer (hidden under this tile's compute)
      if (kt + 1 < NT) {
        char* nb = asmem + (((kt + 1) & 1) << 15);
        int kt1 = kt + 1;
#pragma unroll
        for (int it = 0; it < 4; ++it) {
          int li = it * 256 + tid;
          int r = li >> 4, c = li & 15;
          GLOAD16(K + (size_t)(kt1 * 64 + r) * 128 + (c ^ (r & 7)) * 8, nb + li * 16);
        }
#pragma unroll
        for (int it = 0; it < 4; ++it) {
          int li = it * 256 + tid;
          int r = li >> 3, c = li & 7;
          GLOAD16(Vt + (size_t)r * 2048 + kt1 * 64 + (c ^ (r & 7)) * 8, nb + 16384 + li * 16);
        }
      }

      bool active = (kt * 64 <= qbase + 31);  // wave-uniform
      if (active) {
        const char* k_l = cb;
        const char* v_l = cb + 16384;

        f32x16 s0v = {}, s1v = {};
        PRIO(1);
#pragma unroll
        for (int kc = 0; kc < 8; ++kc) {
          int cg = kc * 2 + hi;
          int sw = l31 & 7;
          short8 kf0 = *(const short8*)(k_l + l31 * 256 + ((cg ^ sw) * 16));
          s0v = __builtin_amdgcn_mfma_f32_32x32x16_bf16(kf0, qf[kc], s0v, 0, 0, 0);
          short8 kf1 = *(const short8*)(k_l + (32 + l31) * 256 + ((cg ^ sw) * 16));
          s1v = __builtin_amdgcn_mfma_f32_32x32x16_bf16(kf1, qf[kc], s1v, 0, 0, 0);
        }
        PRIO(0);

        if (kt * 64 + 63 > qbase) {
          int kvb = kt * 64 + 4 * hi;
#pragma unroll
          for (int r = 0; r < 16; ++r) {
            int kv = kvb + (r & 3) + 8 * (r >> 2);
            if (kv > qrow) s0v[r] = -1e30f;
            if (kv + 32 > qrow) s1v[r] = -1e30f;
          }
        }

        float tmax[16];
#pragma unroll
        for (int i = 0; i < 16; ++i) tmax[i] = fmaxf(s0v[i], s1v[i]);
#pragma unroll
        for (int st = 8; st >= 1; st >>= 1)
#pragma unroll
          for (int i = 0; i < st; ++i) tmax[i] = fmaxf(tmax[i], tmax[i + st]);
        float pmax = fmaxf(tmax[0], __shfl_xor(tmax[0], 32));

        if (!__all(pmax <= m_run + 8.0f)) {
          float mn = fmaxf(m_run, pmax);
          float alpha = exp2f(m_run - mn);
          m_run = mn; l_run *= alpha;
          o0 *= alpha; o1 *= alpha; o2 *= alpha; o3 *= alpha;
        }

#pragma unroll
        for (int i = 0; i < 16; ++i) {
          s0v[i] = exp2f(s0v[i] - m_run);
          s1v[i] = exp2f(s1v[i] - m_run);
        }
        float tsum[16];
#pragma unroll
        for (int i = 0; i < 16; ++i) tsum[i] = s0v[i] + s1v[i];
#pragma unroll
        for (int st = 8; st >= 1; st >>= 1)
#pragma unroll
          for (int i = 0; i < st; ++i) tsum[i] += tsum[i + st];
        float rsum = tsum[0] + __shfl_xor(tsum[0], 32);
        l_run += rsum;

#define BUILD_PA(sv, base, out)                                                \
        {                                                                      \
          unsigned int a_ = cvtpk(sv[base + 0], sv[base + 1]);                 \
          unsigned int c_ = cvtpk(sv[base + 2], sv[base + 3]);                 \
          unsigned int b_ = cvtpk(sv[base + 4], sv[base + 5]);                 \
          unsigned int d_ = cvtpk(sv[base + 6], sv[base + 7]);                 \
          uint2v r0_ = __builtin_amdgcn_permlane32_swap(a_, b_, false, false); \
          uint2v r1_ = __builtin_amdgcn_permlane32_swap(c_, d_, false, false); \
          union { unsigned int u[4]; short8 v; } uu_;                          \
          uu_.u[0] = r0_[0]; uu_.u[1] = r1_[0]; uu_.u[2] = r0_[1]; uu_.u[3] = r1_[1]; \
          out = uu_.v;                                                         \
        }
        short8 pa0, pa1, pa2, pa3;
        BUILD_PA(s0v, 0, pa0);
        BUILD_PA(s0v, 8, pa1);
        BUILD_PA(s1v, 0, pa2);
        BUILD_PA(s1v, 8, pa3);
#undef BUILD_PA

        PRIO(1);
#define PV_STEP(ovar, dt)                                                          \
        {                                                                          \
          int rv_ = dt * 32 + l31;                                                 \
          const char* vb_ = v_l + rv_ * 128;                                       \
          int sw_ = rv_ & 7;                                                       \
          short8 v0_ = *(const short8*)(vb_ + (((0 + hi) ^ sw_) * 16));            \
          ovar = __builtin_amdgcn_mfma_f32_32x32x16_bf16(v0_, pa0, ovar, 0, 0, 0); \
          short8 v1_ = *(const short8*)(vb_ + (((2 + hi) ^ sw_) * 16));            \
          ovar = __builtin_amdgcn_mfma_f32_32x32x16_bf16(v1_, pa1, ovar, 0, 0, 0); \
          short8 v2_ = *(const short8*)(vb_ + (((4 + hi) ^ sw_) * 16));            \
          ovar = __builtin_amdgcn_mfma_f32_32x32x16_bf16(v2_, pa2, ovar, 0, 0, 0); \
          short8 v3_ = *(const short8*)(vb_ + (((6 + hi) ^ sw_) * 16));            \
          ovar = __builtin_amdgcn_mfma_f32_32x32x16_bf16(v3_, pa3, ovar, 0, 0, 0); \
        }
        PV_STEP(o0, 0)
        PV_STEP(o1, 1)
        PV_STEP(o2, 2)
        PV_STEP(o3, 3)
#undef PV_STEP
        PRIO(0);
      }

      VMCNT0();  // next tile's stage complete (issued ~1 compute-phase ago)
      BAR();
    }

    float inv = 1.0f / l_run;
    size_t orow = (size_t)(b * 2048 + qt * 128 + wid * 32 + l31);
    unsigned short* ob_p = ob + orow * 2048 + h * 128;
#define STORE_DT(ovar, dt)                                                         \
    {                                                                              \
      _Pragma("unroll")                                                            \
      for (int rq = 0; rq < 4; ++rq) {                                             \
        unsigned int w0 = cvtpk(ovar[rq * 4 + 0] * inv, ovar[rq * 4 + 1] * inv);   \
        unsigned int w1 = cvtpk(ovar[rq * 4 + 2] * inv, ovar[rq * 4 + 3] * inv);   \
        uint2v st = {w0, w1};                                                      \
        *(uint2v*)(ob_p + dt * 32 + rq * 8 + 4 * hi) = st;                         \
      }                                                                            \
    }
    STORE_DT(o0, 0)
    STORE_DT(o1, 1)
    STORE_DT(o2, 2)
    STORE_DT(o3, 3)
#undef STORE_DT
  }
}

// ---------------- launch ----------------
extern "C" void kernel_launch(void* const* d_in, const int* in_sizes, int n_in,
                              void* d_out, int out_size, void* d_ws, size_t ws_size,
                              hipStream_t stream) {
  const float* x     = (const float*)d_in[0];
  const float* Wqkv  = (const float*)d_in[1];
  const float* bqkv  = (const float*)d_in[2];
  const float* Wproj = (const float*)d_in[3];
  const float* bproj = (const float*)d_in[4];
  float* out = (float*)d_out;

  char* ws = (char*)d_ws;
  unsigned short* x_bf   = (unsigned short*)ws;                         // 32MB, reused as attn_out
  unsigned short* wqkvt  = (unsigned short*)(ws + 33554432);            // 24MB
  unsigned short* wprojt = (unsigned short*)(ws + 33554432 + 25165824); // 8MB
  unsigned short* qb     = (unsigned short*)(ws + 67108864);            // 32MB (pre-scaled)
  unsigned short* kb     = (unsigned short*)(ws + 100663296);           // 32MB
  unsigned short* vtb    = (unsigned short*)(ws + 134217728);           // 32MB [bh][d][t]

  (void)hipFuncSetAttribute((const void*)gemm_qkv256_kernel,
                            hipFuncAttributeMaxDynamicSharedMemorySize, 131072);
  (void)hipFuncSetAttribute((const void*)gemm_proj256_kernel,
                            hipFuncAttributeMaxDynamicSharedMemorySize, 131072);
  (void)hipFuncSetAttribute((const void*)attn_kernel,
                            hipFuncAttributeMaxDynamicSharedMemorySize, 65536);

  cast_bf16_kernel<<<16384, 256, 0, stream>>>(x, x_bf);
  transpose_cast_kernel<<<dim3(192, 64), dim3(32, 8), 0, stream>>>(Wqkv, wqkvt, 2048, 6144);
  transpose_cast_kernel<<<dim3(64, 64), dim3(32, 8), 0, stream>>>(Wproj, wprojt, 2048, 2048);
  gemm_qkv256_kernel<<<768, 512, 131072, stream>>>(x_bf, wqkvt, bqkv, qb, kb, vtb);
  attn_kernel<<<dim3(8, 64), 256, 65536, stream>>>(qb, kb, vtb, x_bf /* attn_out */);
  gemm_proj256_kernel<<<256, 512, 131072, stream>>>(x_bf, wprojt, bproj, out);
}

// Round 7
// 475.462 us; speedup vs baseline: 1.7250x; 1.1122x over previous
//
#include <hip/hip_runtime.h>
#include <hip/hip_bf16.h>
#include <stdint.h>

typedef __attribute__((ext_vector_type(8))) short short8;
typedef __attribute__((ext_vector_type(4))) float f32x4;
typedef __attribute__((ext_vector_type(16))) float f32x16;
typedef __attribute__((ext_vector_type(2))) unsigned int uint2v;

__device__ __forceinline__ unsigned short f2bf(float f) {
  union { float f; unsigned int u; } v; v.f = f;
  unsigned int r = v.u + 0x7FFFu + ((v.u >> 16) & 1u);
  return (unsigned short)(r >> 16);
}

__device__ __forceinline__ unsigned int cvtpk(float lo, float hi) {
  unsigned int r;
  asm("v_cvt_pk_bf16_f32 %0, %1, %2" : "=v"(r) : "v"(lo), "v"(hi));
  return r;
}

#define GLOAD16(gsrc, ldst)                                                                  \
  __builtin_amdgcn_global_load_lds((const __attribute__((address_space(1))) void*)(gsrc),    \
                                   (__attribute__((address_space(3))) void*)(ldst), 16, 0, 0)

#define BAR() __builtin_amdgcn_s_barrier()
#define LGKM0() do { asm volatile("s_waitcnt lgkmcnt(0)" ::: "memory"); \
                     __builtin_amdgcn_sched_barrier(0); } while (0)
#define VMCNT0() asm volatile("s_waitcnt vmcnt(0)" ::: "memory")
#define VMCNT8() asm volatile("s_waitcnt vmcnt(8)" ::: "memory")
#define PRIO(x) __builtin_amdgcn_s_setprio(x)

// ---------------- cast x (fp32 -> bf16), 4 elems/thread ----------------
__global__ __launch_bounds__(256) void cast_bf16_kernel(const float* __restrict__ in,
                                                        unsigned short* __restrict__ out) {
  int i = blockIdx.x * 256 + threadIdx.x;
  float4 v = ((const float4*)in)[i];
  ushort4 o;
  o.x = f2bf(v.x); o.y = f2bf(v.y); o.z = f2bf(v.z); o.w = f2bf(v.w);
  ((ushort4*)out)[i] = o;
}

// ---------------- transpose + cast W: [K][N] fp32 -> [N][K] bf16 ----------------
__global__ __launch_bounds__(256) void transpose_cast_kernel(const float* __restrict__ W,
                                                             unsigned short* __restrict__ Wt,
                                                             int K, int N) {
  __shared__ float tile[32][33];
  int n0 = blockIdx.x * 32, k0 = blockIdx.y * 32;
  int tx = threadIdx.x, ty = threadIdx.y;
#pragma unroll
  for (int j = 0; j < 32; j += 8)
    tile[ty + j][tx] = W[(size_t)(k0 + ty + j) * N + n0 + tx];
  __syncthreads();
#pragma unroll
  for (int j = 0; j < 32; j += 8)
    Wt[(size_t)(n0 + ty + j) * K + k0 + tx] = f2bf(tile[tx][ty + j]);
}

// ---------------- 256x256 8-phase GEMM mainloop (T2+T3+T4+T5) ----------------
// Stage schedule: P2: B0(t+2), P3: B1(t+2), P4: A0(t+2)+A1(t+2); vmcnt(8) at tile end
// forces all of tile t+1's 8 loads complete. A-latency cover ~4.5 phases, B ~6-7.
__device__ __forceinline__ void stage_half(const unsigned short* __restrict__ gp, int K,
                                           int kt, int half, char* lds_mat, int tid) {
#pragma unroll
  for (int it = 0; it < 2; ++it) {
    int li = half * 1024 + it * 512 + tid;  // 16B-chunk index in 256x64 tile
    int r = li >> 3, c = li & 7;
    int cs = c ^ (r & 7);
    GLOAD16(gp + (size_t)r * K + kt * 64 + cs * 8, lds_mat + li * 16);
  }
}

__device__ __forceinline__ void gemm256_mainloop(const unsigned short* __restrict__ Ap,
                                                 const unsigned short* __restrict__ Bp,
                                                 int K, int tid, char* smem,
                                                 f32x4 acc[8][4]) {
  char* sa = smem;           // A: 2 bufs x 32768 B
  char* sb = smem + 65536;   // B: 2 bufs x 32768 B
  const int KT = K >> 6;     // 32

  int wid = tid >> 6, lane = tid & 63;
  int wr = wid >> 2, wc = wid & 3;
  int lg = lane >> 4, l15 = lane & 15;
  int swz7 = l15 & 7;

  // prologue: t0 fully (oldest 8 loads), then t1 fully (next 8)
  stage_half(Bp, K, 0, 0, sb, tid);
  stage_half(Bp, K, 0, 1, sb, tid);
  stage_half(Ap, K, 0, 0, sa, tid);
  stage_half(Ap, K, 0, 1, sa, tid);
  stage_half(Bp, K, 1, 0, sb + 32768, tid);
  stage_half(Bp, K, 1, 1, sb + 32768, tid);
  stage_half(Ap, K, 1, 0, sa + 32768, tid);
  stage_half(Ap, K, 1, 1, sa + 32768, tid);
  VMCNT8();  // forces t0's 8 loads (t1's 8 stay in flight)
  BAR();

#define LDA(ab, m, kc) \
  (*(const short8*)((ab) + (size_t)((wr * 128 + (m) * 16 + l15) * 64 + ((((kc) * 4 + lg) ^ swz7) * 8))))
#define LDB(bb, n, kc) \
  (*(const short8*)((bb) + (size_t)((wc * 64 + (n) * 16 + l15) * 64 + ((((kc) * 4 + lg) ^ swz7) * 8))))

  for (int t = 0; t < KT; ++t) {
    int p = t & 1;
    const unsigned short* ab = (const unsigned short*)(sa + p * 32768);
    const unsigned short* bb = (const unsigned short*)(sb + p * 32768);
    int kt2 = (t + 2 < KT) ? t + 2 : KT - 1;

    short8 bq[4][2], aq[4][2];
    // ---- P1: read B(all) + A(m0-3); Q1 = m0-3 x n0-1 ----
#pragma unroll
    for (int n = 0; n < 4; ++n) { bq[n][0] = LDB(bb, n, 0); bq[n][1] = LDB(bb, n, 1); }
#pragma unroll
    for (int m = 0; m < 4; ++m) { aq[m][0] = LDA(ab, m, 0); aq[m][1] = LDA(ab, m, 1); }
    BAR();
    LGKM0();
    PRIO(1);
#pragma unroll
    for (int kc = 0; kc < 2; ++kc)
#pragma unroll
      for (int m = 0; m < 4; ++m)
#pragma unroll
        for (int n = 0; n < 2; ++n)
          acc[m][n] = __builtin_amdgcn_mfma_f32_16x16x32_bf16(aq[m][kc], bq[n][kc], acc[m][n], 0, 0, 0);
    PRIO(0);
    BAR();

    // ---- P2: stage B0(t+2); Q2 = m0-3 x n2-3 ----
    stage_half(Bp, K, kt2, 0, sb + p * 32768, tid);
    BAR();
    PRIO(1);
#pragma unroll
    for (int kc = 0; kc < 2; ++kc)
#pragma unroll
      for (int m = 0; m < 4; ++m)
#pragma unroll
        for (int n = 2; n < 4; ++n)
          acc[m][n] = __builtin_amdgcn_mfma_f32_16x16x32_bf16(aq[m][kc], bq[n][kc], acc[m][n], 0, 0, 0);
    PRIO(0);
    BAR();

    // ---- P3: read A(m4-7); stage B1(t+2); Q3 = m4-7 x n2-3 ----
#pragma unroll
    for (int m = 0; m < 4; ++m) { aq[m][0] = LDA(ab, m + 4, 0); aq[m][1] = LDA(ab, m + 4, 1); }
    stage_half(Bp, K, kt2, 1, sb + p * 32768, tid);
    BAR();
    LGKM0();
    PRIO(1);
#pragma unroll
    for (int kc = 0; kc < 2; ++kc)
#pragma unroll
      for (int m = 0; m < 4; ++m)
#pragma unroll
        for (int n = 2; n < 4; ++n)
          acc[m + 4][n] = __builtin_amdgcn_mfma_f32_16x16x32_bf16(aq[m][kc], bq[n][kc], acc[m + 4][n], 0, 0, 0);
    PRIO(0);
    BAR();

    // ---- P4: stage A0(t+2)+A1(t+2); Q4 = m4-7 x n0-1; vmcnt(8) ----
    stage_half(Ap, K, kt2, 0, sa + p * 32768, tid);
    stage_half(Ap, K, kt2, 1, sa + p * 32768, tid);
    BAR();
    PRIO(1);
#pragma unroll
    for (int kc = 0; kc < 2; ++kc)
#pragma unroll
      for (int m = 0; m < 4; ++m)
#pragma unroll
        for (int n = 0; n < 2; ++n)
          acc[m + 4][n] = __builtin_amdgcn_mfma_f32_16x16x32_bf16(aq[m][kc], bq[n][kc], acc[m + 4][n], 0, 0, 0);
    PRIO(0);
    VMCNT8();
    BAR();
  }
#undef LDA
#undef LDB
}

// ---------------- QKV GEMM 256^2: chunked XCD map; scatter q (pre-scaled) / k; v^T via LDS transpose ----------------
__global__ __launch_bounds__(512, 2) void gemm_qkv256_kernel(const unsigned short* __restrict__ A,
                                                             const unsigned short* __restrict__ Bt,
                                                             const float* __restrict__ bias,
                                                             unsigned short* __restrict__ qb,
                                                             unsigned short* __restrict__ kb,
                                                             unsigned short* __restrict__ vtb) {
  extern __shared__ char smem[];
  int wg = blockIdx.x;                 // 768 blocks
  int xcd = wg & 7, idx = wg >> 3;     // 96 per XCD
  int bn = xcd * 3 + idx % 3;          // bn-fast: 3 concurrent blocks share each A-panel in L2
  int bm = idx / 3;                    // 0..31
  int tid = threadIdx.x;

  f32x4 acc[8][4];
  f32x4 zero = {0.f, 0.f, 0.f, 0.f};
#pragma unroll
  for (int m = 0; m < 8; ++m)
#pragma unroll
    for (int n = 0; n < 4; ++n) acc[m][n] = zero;

  gemm256_mainloop(A + (size_t)bm * 256 * 2048, Bt + (size_t)bn * 256 * 2048, 2048, tid, smem, acc);

  const float QSCALE = (float)(0.08838834764831845 * 1.4426950408889634);  // D^-0.5 * log2(e)
  int wid = tid >> 6, lane = tid & 63;
  int wr = wid >> 2, wc = wid & 3, lg = lane >> 4, l15 = lane & 15;
  int l31 = lane & 31, hi = lane >> 5;

  if (bn >= 16) {
    // ---- v-block: transpose 256x256 tile via LDS, write [bh][d][t] coalesced ----
    VMCNT0();  // drain tail junk prefetches before reusing LDS
    BAR();
#pragma unroll
    for (int n = 0; n < 4; ++n) {
      int cl = wc * 64 + n * 16 + l15;
      float bv = bias[bn * 256 + cl];
#pragma unroll
      for (int m = 0; m < 8; ++m) {
        int rl = wr * 128 + m * 16 + lg * 4;
        unsigned int w0 = cvtpk(acc[m][n][0] + bv, acc[m][n][1] + bv);
        unsigned int w1 = cvtpk(acc[m][n][2] + bv, acc[m][n][3] + bv);
        uint2v pk = {w0, w1};
        *(uint2v*)(smem + cl * 512 + ((rl * 2) ^ ((cl & 7) << 4))) = pk;
      }
    }
    LGKM0();
    BAR();
    int t0_abs = bm * 256;
    int bq_ = t0_abs >> 11, t0 = t0_abs & 2047;
    int h0 = (bn * 256 - 4096) >> 7;  // first of 2 heads in this block
#pragma unroll
    for (int i = 0; i < 16; ++i) {
      int dloc = i * 16 + wid * 2 + hi;  // 0..255
      short8 vrow = *(const short8*)(smem + dloc * 512 + ((l31 * 16) ^ ((dloc & 7) << 4)));
      int bh_ = bq_ * 16 + h0 + (dloc >> 7);
      int d = dloc & 127;
      *(short8*)(vtb + ((size_t)bh_ * 128 + d) * 2048 + t0 + l31 * 8) = vrow;
    }
  } else {
    // ---- q/k block: direct scatter ----
#pragma unroll
    for (int n = 0; n < 4; ++n) {
      int col = bn * 256 + wc * 64 + n * 16 + l15;  // [0,4096)
      float bv = bias[col];
      int which = col >> 11;       // 0=q 1=k (block-uniform)
      int h = (col & 2047) >> 7;
      int d = col & 127;
#pragma unroll
      for (int m = 0; m < 8; ++m) {
#pragma unroll
        for (int g = 0; g < 4; ++g) {
          int row = bm * 256 + wr * 128 + m * 16 + lg * 4 + g;  // [0,8192)
          int b = row >> 11, t = row & 2047;
          float r = acc[m][n][g] + bv;
          if (which == 0) r *= QSCALE;
          unsigned short val = f2bf(r);
          size_t bhi = (size_t)(b * 16 + h);
          if (which == 0) qb[(bhi * 2048 + t) * 128 + d] = val;
          else            kb[(bhi * 2048 + t) * 128 + d] = val;
        }
      }
    }
  }
}

// ---------------- Proj GEMM 256^2: fp32 output + bias ----------------
__global__ __launch_bounds__(512, 2) void gemm_proj256_kernel(const unsigned short* __restrict__ A,
                                                              const unsigned short* __restrict__ Bt,
                                                              const float* __restrict__ bias,
                                                              float* __restrict__ out) {
  extern __shared__ char smem[];
  int wg = blockIdx.x;
  int bm = wg >> 3, bn = wg & 7;  // one bn column per XCD; B-panel L2-resident
  int tid = threadIdx.x;

  f32x4 acc[8][4];
  f32x4 zero = {0.f, 0.f, 0.f, 0.f};
#pragma unroll
  for (int m = 0; m < 8; ++m)
#pragma unroll
    for (int n = 0; n < 4; ++n) acc[m][n] = zero;

  gemm256_mainloop(A + (size_t)bm * 256 * 2048, Bt + (size_t)bn * 256 * 2048, 2048, tid, smem, acc);

  int wid = tid >> 6, lane = tid & 63;
  int wr = wid >> 2, wc = wid & 3, lg = lane >> 4, l15 = lane & 15;
#pragma unroll
  for (int n = 0; n < 4; ++n) {
    int col = bn * 256 + wc * 64 + n * 16 + l15;
    float bv = bias[col];
#pragma unroll
    for (int m = 0; m < 8; ++m) {
#pragma unroll
      for (int g = 0; g < 4; ++g) {
        int row = bm * 256 + wr * 128 + m * 16 + lg * 4 + g;
        out[(size_t)row * 2048 + col] = acc[m][n][g] + bv;
      }
    }
  }
}

// ---------------- Flash attention: paired q-tiles, double-buffered K/V, 2-phase pipeline ----------------
__global__ __launch_bounds__(256) void attn_kernel(const unsigned short* __restrict__ qb,
                                                   const unsigned short* __restrict__ kb,
                                                   const unsigned short* __restrict__ vtb,
                                                   unsigned short* __restrict__ ob) {
  extern __shared__ char asmem[];
  int pairi = blockIdx.x;  // 0..7
  int bh = blockIdx.y;
  int b = bh >> 4, h = bh & 15;
  int tid = threadIdx.x, wid = tid >> 6, lane = tid & 63;
  int l31 = lane & 31, hi = lane >> 5;

  const unsigned short* Q  = qb  + (size_t)bh * 2048 * 128;
  const unsigned short* K  = kb  + (size_t)bh * 2048 * 128;
  const unsigned short* Vt = vtb + (size_t)bh * 128 * 2048;

#pragma unroll 1
  for (int pass = 0; pass < 2; ++pass) {
    int qt = pass == 0 ? (15 - pairi) : pairi;
    int NT = 2 * qt + 2;
    int qbase = qt * 128 + wid * 32;
    int qrow = qbase + l31;

    short8 qf[8];
#pragma unroll
    for (int kc = 0; kc < 8; ++kc)
      qf[kc] = *(const short8*)(Q + (size_t)qrow * 128 + kc * 16 + hi * 8);

    f32x16 o0 = {}, o1 = {}, o2 = {}, o3 = {};  // O^T[d][q=l31]
    float m_run = -1e30f, l_run = 0.f;

    // prologue: stage tile 0 into buf0
    {
      char* kb_ = asmem;
#pragma unroll
      for (int it = 0; it < 4; ++it) {
        int li = it * 256 + tid;
        int r = li >> 4, c = li & 15;
        GLOAD16(K + (size_t)r * 128 + (c ^ (r & 7)) * 8, kb_ + li * 16);
      }
#pragma unroll
      for (int it = 0; it < 4; ++it) {
        int li = it * 256 + tid;
        int r = li >> 3, c = li & 7;
        GLOAD16(Vt + (size_t)r * 2048 + (c ^ (r & 7)) * 8, kb_ + 16384 + li * 16);
      }
    }
    VMCNT0();
    BAR();

#pragma unroll 1
    for (int kt = 0; kt < NT; ++kt) {
      char* cb = asmem + ((kt & 1) << 15);
      // stage next tile into the other buffer (hidden under this tile's compute)
      if (kt + 1 < NT) {
        char* nb = asmem + (((kt + 1) & 1) << 15);
        int kt1 = kt + 1;
#pragma unroll
        for (int it = 0; it < 4; ++it) {
          int li = it * 256 + tid;
          int r = li >> 4, c = li & 15;
          GLOAD16(K + (size_t)(kt1 * 64 + r) * 128 + (c ^ (r & 7)) * 8, nb + li * 16);
        }
#pragma unroll
        for (int it = 0; it < 4; ++it) {
          int li = it * 256 + tid;
          int r = li >> 3, c = li & 7;
          GLOAD16(Vt + (size_t)r * 2048 + kt1 * 64 + (c ^ (r & 7)) * 8, nb + 16384 + li * 16);
        }
      }

      bool active = (kt * 64 <= qbase + 31);  // wave-uniform
      if (active) {
        const char* k_l = cb;
        const char* v_l = cb + 16384;

        f32x16 s0v = {}, s1v = {};
        PRIO(1);
#pragma unroll
        for (int kc = 0; kc < 8; ++kc) {
          int cg = kc * 2 + hi;
          int sw = l31 & 7;
          short8 kf0 = *(const short8*)(k_l + l31 * 256 + ((cg ^ sw) * 16));
          s0v = __builtin_amdgcn_mfma_f32_32x32x16_bf16(kf0, qf[kc], s0v, 0, 0, 0);
          short8 kf1 = *(const short8*)(k_l + (32 + l31) * 256 + ((cg ^ sw) * 16));
          s1v = __builtin_amdgcn_mfma_f32_32x32x16_bf16(kf1, qf[kc], s1v, 0, 0, 0);
        }
        PRIO(0);

        if (kt * 64 + 63 > qbase) {
          int kvb = kt * 64 + 4 * hi;
#pragma unroll
          for (int r = 0; r < 16; ++r) {
            int kv = kvb + (r & 3) + 8 * (r >> 2);
            if (kv > qrow) s0v[r] = -1e30f;
            if (kv + 32 > qrow) s1v[r] = -1e30f;
          }
        }

        float tmax[16];
#pragma unroll
        for (int i = 0; i < 16; ++i) tmax[i] = fmaxf(s0v[i], s1v[i]);
#pragma unroll
        for (int st = 8; st >= 1; st >>= 1)
#pragma unroll
          for (int i = 0; i < st; ++i) tmax[i] = fmaxf(tmax[i], tmax[i + st]);
        float pmax = fmaxf(tmax[0], __shfl_xor(tmax[0], 32));

        if (!__all(pmax <= m_run + 8.0f)) {
          float mn = fmaxf(m_run, pmax);
          float alpha = exp2f(m_run - mn);
          m_run = mn; l_run *= alpha;
          o0 *= alpha; o1 *= alpha; o2 *= alpha; o3 *= alpha;
        }

#pragma unroll
        for (int i = 0; i < 16; ++i) {
          s0v[i] = exp2f(s0v[i] - m_run);
          s1v[i] = exp2f(s1v[i] - m_run);
        }
        float tsum[16];
#pragma unroll
        for (int i = 0; i < 16; ++i) tsum[i] = s0v[i] + s1v[i];
#pragma unroll
        for (int st = 8; st >= 1; st >>= 1)
#pragma unroll
          for (int i = 0; i < st; ++i) tsum[i] += tsum[i + st];
        float rsum = tsum[0] + __shfl_xor(tsum[0], 32);
        l_run += rsum;

#define BUILD_PA(sv, base, out)                                                \
        {                                                                      \
          unsigned int a_ = cvtpk(sv[base + 0], sv[base + 1]);                 \
          unsigned int c_ = cvtpk(sv[base + 2], sv[base + 3]);                 \
          unsigned int b_ = cvtpk(sv[base + 4], sv[base + 5]);                 \
          unsigned int d_ = cvtpk(sv[base + 6], sv[base + 7]);                 \
          uint2v r0_ = __builtin_amdgcn_permlane32_swap(a_, b_, false, false); \
          uint2v r1_ = __builtin_amdgcn_permlane32_swap(c_, d_, false, false); \
          union { unsigned int u[4]; short8 v; } uu_;                          \
          uu_.u[0] = r0_[0]; uu_.u[1] = r1_[0]; uu_.u[2] = r0_[1]; uu_.u[3] = r1_[1]; \
          out = uu_.v;                                                         \
        }
        short8 pa0, pa1, pa2, pa3;
        BUILD_PA(s0v, 0, pa0);
        BUILD_PA(s0v, 8, pa1);
        BUILD_PA(s1v, 0, pa2);
        BUILD_PA(s1v, 8, pa3);
#undef BUILD_PA

        PRIO(1);
#define PV_STEP(ovar, dt)                                                          \
        {                                                                          \
          int rv_ = dt * 32 + l31;                                                 \
          const char* vb_ = v_l + rv_ * 128;                                       \
          int sw_ = rv_ & 7;                                                       \
          short8 v0_ = *(const short8*)(vb_ + (((0 + hi) ^ sw_) * 16));            \
          ovar = __builtin_amdgcn_mfma_f32_32x32x16_bf16(v0_, pa0, ovar, 0, 0, 0); \
          short8 v1_ = *(const short8*)(vb_ + (((2 + hi) ^ sw_) * 16));            \
          ovar = __builtin_amdgcn_mfma_f32_32x32x16_bf16(v1_, pa1, ovar, 0, 0, 0); \
          short8 v2_ = *(const short8*)(vb_ + (((4 + hi) ^ sw_) * 16));            \
          ovar = __builtin_amdgcn_mfma_f32_32x32x16_bf16(v2_, pa2, ovar, 0, 0, 0); \
          short8 v3_ = *(const short8*)(vb_ + (((6 + hi) ^ sw_) * 16));            \
          ovar = __builtin_amdgcn_mfma_f32_32x32x16_bf16(v3_, pa3, ovar, 0, 0, 0); \
        }
        PV_STEP(o0, 0)
        PV_STEP(o1, 1)
        PV_STEP(o2, 2)
        PV_STEP(o3, 3)
#undef PV_STEP
        PRIO(0);
      }

      VMCNT0();  // next tile's stage complete (issued ~1 compute-phase ago)
      BAR();
    }

    float inv = 1.0f / l_run;
    size_t orow = (size_t)(b * 2048 + qt * 128 + wid * 32 + l31);
    unsigned short* ob_p = ob + orow * 2048 + h * 128;
#define STORE_DT(ovar, dt)                                                         \
    {                                                                              \
      _Pragma("unroll")                                                            \
      for (int rq = 0; rq < 4; ++rq) {                                             \
        unsigned int w0 = cvtpk(ovar[rq * 4 + 0] * inv, ovar[rq * 4 + 1] * inv);   \
        unsigned int w1 = cvtpk(ovar[rq * 4 + 2] * inv, ovar[rq * 4 + 3] * inv);   \
        uint2v st = {w0, w1};                                                      \
        *(uint2v*)(ob_p + dt * 32 + rq * 8 + 4 * hi) = st;                         \
      }                                                                            \
    }
    STORE_DT(o0, 0)
    STORE_DT(o1, 1)
    STORE_DT(o2, 2)
    STORE_DT(o3, 3)
#undef STORE_DT
  }
}

// ---------------- launch ----------------
extern "C" void kernel_launch(void* const* d_in, const int* in_sizes, int n_in,
                              void* d_out, int out_size, void* d_ws, size_t ws_size,
                              hipStream_t stream) {
  const float* x     = (const float*)d_in[0];
  const float* Wqkv  = (const float*)d_in[1];
  const float* bqkv  = (const float*)d_in[2];
  const float* Wproj = (const float*)d_in[3];
  const float* bproj = (const float*)d_in[4];
  float* out = (float*)d_out;

  char* ws = (char*)d_ws;
  unsigned short* x_bf   = (unsigned short*)ws;                         // 32MB, reused as attn_out
  unsigned short* wqkvt  = (unsigned short*)(ws + 33554432);            // 24MB
  unsigned short* wprojt = (unsigned short*)(ws + 33554432 + 25165824); // 8MB
  unsigned short* qb     = (unsigned short*)(ws + 67108864);            // 32MB (pre-scaled)
  unsigned short* kb     = (unsigned short*)(ws + 100663296);           // 32MB
  unsigned short* vtb    = (unsigned short*)(ws + 134217728);           // 32MB [bh][d][t]

  (void)hipFuncSetAttribute((const void*)gemm_qkv256_kernel,
                            hipFuncAttributeMaxDynamicSharedMemorySize, 131072);
  (void)hipFuncSetAttribute((const void*)gemm_proj256_kernel,
                            hipFuncAttributeMaxDynamicSharedMemorySize, 131072);
  (void)hipFuncSetAttribute((const void*)attn_kernel,
                            hipFuncAttributeMaxDynamicSharedMemorySize, 65536);

  cast_bf16_kernel<<<16384, 256, 0, stream>>>(x, x_bf);
  transpose_cast_kernel<<<dim3(192, 64), dim3(32, 8), 0, stream>>>(Wqkv, wqkvt, 2048, 6144);
  transpose_cast_kernel<<<dim3(64, 64), dim3(32, 8), 0, stream>>>(Wproj, wprojt, 2048, 2048);
  gemm_qkv256_kernel<<<768, 512, 131072, stream>>>(x_bf, wqkvt, bqkv, qb, kb, vtb);
  attn_kernel<<<dim3(8, 64), 256, 65536, stream>>>(qb, kb, vtb, x_bf /* attn_out */);
  gemm_proj256_kernel<<<256, 512, 131072, stream>>>(x_bf, wprojt, bproj, out);
}

// Round 8
// 467.317 us; speedup vs baseline: 1.7550x; 1.0174x over previous
//
#include <hip/hip_runtime.h>
#include <hip/hip_bf16.h>
#include <stdint.h>

typedef __attribute__((ext_vector_type(8))) short short8;
typedef __attribute__((ext_vector_type(4))) float f32x4;
typedef __attribute__((ext_vector_type(16))) float f32x16;
typedef __attribute__((ext_vector_type(2))) unsigned int uint2v;

__device__ __forceinline__ unsigned short f2bf(float f) {
  union { float f; unsigned int u; } v; v.f = f;
  unsigned int r = v.u + 0x7FFFu + ((v.u >> 16) & 1u);
  return (unsigned short)(r >> 16);
}

__device__ __forceinline__ unsigned int cvtpk(float lo, float hi) {
  unsigned int r;
  asm("v_cvt_pk_bf16_f32 %0, %1, %2" : "=v"(r) : "v"(lo), "v"(hi));
  return r;
}

#define GLOAD16(gsrc, ldst)                                                                  \
  __builtin_amdgcn_global_load_lds((const __attribute__((address_space(1))) void*)(gsrc),    \
                                   (__attribute__((address_space(3))) void*)(ldst), 16, 0, 0)

#define BAR() __builtin_amdgcn_s_barrier()
#define LGKM0() do { asm volatile("s_waitcnt lgkmcnt(0)" ::: "memory"); \
                     __builtin_amdgcn_sched_barrier(0); } while (0)
#define VMCNT0() asm volatile("s_waitcnt vmcnt(0)" ::: "memory")
#define VMCNT8() asm volatile("s_waitcnt vmcnt(8)" ::: "memory")
#define PRIO(x) __builtin_amdgcn_s_setprio(x)

// ---------------- cast x (fp32 -> bf16), 4 elems/thread ----------------
__global__ __launch_bounds__(256) void cast_bf16_kernel(const float* __restrict__ in,
                                                        unsigned short* __restrict__ out) {
  int i = blockIdx.x * 256 + threadIdx.x;
  float4 v = ((const float4*)in)[i];
  ushort4 o;
  o.x = f2bf(v.x); o.y = f2bf(v.y); o.z = f2bf(v.z); o.w = f2bf(v.w);
  ((ushort4*)out)[i] = o;
}

// ---------------- transpose + cast W: [K][N] fp32 -> [N][K] bf16 ----------------
__global__ __launch_bounds__(256) void transpose_cast_kernel(const float* __restrict__ W,
                                                             unsigned short* __restrict__ Wt,
                                                             int K, int N) {
  __shared__ float tile[32][33];
  int n0 = blockIdx.x * 32, k0 = blockIdx.y * 32;
  int tx = threadIdx.x, ty = threadIdx.y;
#pragma unroll
  for (int j = 0; j < 32; j += 8)
    tile[ty + j][tx] = W[(size_t)(k0 + ty + j) * N + n0 + tx];
  __syncthreads();
#pragma unroll
  for (int j = 0; j < 32; j += 8)
    Wt[(size_t)(n0 + ty + j) * K + k0 + tx] = f2bf(tile[tx][ty + j]);
}

// ---------------- 256x256 GEMM mainloop, 4-phase / 4-barrier schedule ----------------
// Barriers per tile: P1-pre (align reads/MFMA), P1-post (B-reads drained before B-stage),
// P3-post (A-reads drained before A-stage), tile-end vmcnt(8)+BAR (next buffer ready).
// P2/P4 are register-only MFMA phases and need no barriers.
__device__ __forceinline__ void stage_half(const unsigned short* __restrict__ gp, int K,
                                           int kt, int half, char* lds_mat, int tid) {
#pragma unroll
  for (int it = 0; it < 2; ++it) {
    int li = half * 1024 + it * 512 + tid;  // 16B-chunk index in 256x64 tile
    int r = li >> 3, c = li & 7;
    int cs = c ^ (r & 7);
    GLOAD16(gp + (size_t)r * K + kt * 64 + cs * 8, lds_mat + li * 16);
  }
}

__device__ __forceinline__ void gemm256_mainloop(const unsigned short* __restrict__ Ap,
                                                 const unsigned short* __restrict__ Bp,
                                                 int K, int tid, char* smem,
                                                 f32x4 acc[8][4]) {
  char* sa = smem;           // A: 2 bufs x 32768 B
  char* sb = smem + 65536;   // B: 2 bufs x 32768 B
  const int KT = K >> 6;     // 32

  int wid = tid >> 6, lane = tid & 63;
  int wr = wid >> 2, wc = wid & 3;
  int lg = lane >> 4, l15 = lane & 15;
  int swz7 = l15 & 7;

  // prologue: t0 fully (oldest 8 loads), then t1 fully (next 8)
  stage_half(Bp, K, 0, 0, sb, tid);
  stage_half(Bp, K, 0, 1, sb, tid);
  stage_half(Ap, K, 0, 0, sa, tid);
  stage_half(Ap, K, 0, 1, sa, tid);
  stage_half(Bp, K, 1, 0, sb + 32768, tid);
  stage_half(Bp, K, 1, 1, sb + 32768, tid);
  stage_half(Ap, K, 1, 0, sa + 32768, tid);
  stage_half(Ap, K, 1, 1, sa + 32768, tid);
  VMCNT8();  // forces t0's 8 loads (t1's 8 stay in flight)
  BAR();

#define LDA(ab, m, kc) \
  (*(const short8*)((ab) + (size_t)((wr * 128 + (m) * 16 + l15) * 64 + ((((kc) * 4 + lg) ^ swz7) * 8))))
#define LDB(bb, n, kc) \
  (*(const short8*)((bb) + (size_t)((wc * 64 + (n) * 16 + l15) * 64 + ((((kc) * 4 + lg) ^ swz7) * 8))))

  for (int t = 0; t < KT; ++t) {
    int p = t & 1;
    const unsigned short* ab = (const unsigned short*)(sa + p * 32768);
    const unsigned short* bb = (const unsigned short*)(sb + p * 32768);
    int kt2 = (t + 2 < KT) ? t + 2 : KT - 1;

    short8 bq[4][2], aq[4][2], aq2[4][2];
    // ---- P1: read B(all) + A(m0-3); Q1 = m0-3 x n0-1 ----
#pragma unroll
    for (int n = 0; n < 4; ++n) { bq[n][0] = LDB(bb, n, 0); bq[n][1] = LDB(bb, n, 1); }
#pragma unroll
    for (int m = 0; m < 4; ++m) { aq[m][0] = LDA(ab, m, 0); aq[m][1] = LDA(ab, m, 1); }
    BAR();
    LGKM0();
    PRIO(1);
#pragma unroll
    for (int kc = 0; kc < 2; ++kc)
#pragma unroll
      for (int m = 0; m < 4; ++m)
#pragma unroll
        for (int n = 0; n < 2; ++n)
          acc[m][n] = __builtin_amdgcn_mfma_f32_16x16x32_bf16(aq[m][kc], bq[n][kc], acc[m][n], 0, 0, 0);
    PRIO(0);
    BAR();  // B-reads (all waves) drained -> B-staging safe

    // ---- P2 (no barrier): stage B0(t+2); issue A(m4-7) reads; Q2 = m0-3 x n2-3 ----
    stage_half(Bp, K, kt2, 0, sb + p * 32768, tid);
#pragma unroll
    for (int m = 0; m < 4; ++m) { aq2[m][0] = LDA(ab, m + 4, 0); aq2[m][1] = LDA(ab, m + 4, 1); }
    PRIO(1);
#pragma unroll
    for (int kc = 0; kc < 2; ++kc)
#pragma unroll
      for (int m = 0; m < 4; ++m)
#pragma unroll
        for (int n = 2; n < 4; ++n)
          acc[m][n] = __builtin_amdgcn_mfma_f32_16x16x32_bf16(aq[m][kc], bq[n][kc], acc[m][n], 0, 0, 0);
    PRIO(0);

    // ---- P3: stage B1(t+2); Q3 = m4-7 x n2-3 ----
    stage_half(Bp, K, kt2, 1, sb + p * 32768, tid);
    LGKM0();
    PRIO(1);
#pragma unroll
    for (int kc = 0; kc < 2; ++kc)
#pragma unroll
      for (int m = 0; m < 4; ++m)
#pragma unroll
        for (int n = 2; n < 4; ++n)
          acc[m + 4][n] = __builtin_amdgcn_mfma_f32_16x16x32_bf16(aq2[m][kc], bq[n][kc], acc[m + 4][n], 0, 0, 0);
    PRIO(0);
    BAR();  // A-reads (all waves) drained -> A-staging safe

    // ---- P4 (no pre-barrier): stage A0+A1(t+2); Q4 = m4-7 x n0-1; vmcnt(8) ----
    stage_half(Ap, K, kt2, 0, sa + p * 32768, tid);
    stage_half(Ap, K, kt2, 1, sa + p * 32768, tid);
    PRIO(1);
#pragma unroll
    for (int kc = 0; kc < 2; ++kc)
#pragma unroll
      for (int m = 0; m < 4; ++m)
#pragma unroll
        for (int n = 0; n < 2; ++n)
          acc[m + 4][n] = __builtin_amdgcn_mfma_f32_16x16x32_bf16(aq2[m][kc], bq[n][kc], acc[m + 4][n], 0, 0, 0);
    PRIO(0);
    VMCNT8();
    BAR();  // next tile's buffer ready for all waves
  }
#undef LDA
#undef LDB
}

// ---------------- QKV GEMM 256^2: chunked XCD map; scatter q (pre-scaled) / k; v^T via LDS transpose ----------------
__global__ __launch_bounds__(512, 2) void gemm_qkv256_kernel(const unsigned short* __restrict__ A,
                                                             const unsigned short* __restrict__ Bt,
                                                             const float* __restrict__ bias,
                                                             unsigned short* __restrict__ qb,
                                                             unsigned short* __restrict__ kb,
                                                             unsigned short* __restrict__ vtb) {
  extern __shared__ char smem[];
  int wg = blockIdx.x;                 // 768 blocks
  int xcd = wg & 7, idx = wg >> 3;     // 96 per XCD
  int bn = xcd * 3 + idx % 3;          // bn-fast: 3 concurrent blocks share each A-panel in L2
  int bm = idx / 3;                    // 0..31
  int tid = threadIdx.x;

  f32x4 acc[8][4];
  f32x4 zero = {0.f, 0.f, 0.f, 0.f};
#pragma unroll
  for (int m = 0; m < 8; ++m)
#pragma unroll
    for (int n = 0; n < 4; ++n) acc[m][n] = zero;

  gemm256_mainloop(A + (size_t)bm * 256 * 2048, Bt + (size_t)bn * 256 * 2048, 2048, tid, smem, acc);

  const float QSCALE = (float)(0.08838834764831845 * 1.4426950408889634);  // D^-0.5 * log2(e)
  int wid = tid >> 6, lane = tid & 63;
  int wr = wid >> 2, wc = wid & 3, lg = lane >> 4, l15 = lane & 15;
  int l31 = lane & 31, hi = lane >> 5;

  if (bn >= 16) {
    // ---- v-block: transpose 256x256 tile via LDS, write [bh][d][t] coalesced ----
    VMCNT0();  // drain tail junk prefetches before reusing LDS
    BAR();
#pragma unroll
    for (int n = 0; n < 4; ++n) {
      int cl = wc * 64 + n * 16 + l15;
      float bv = bias[bn * 256 + cl];
#pragma unroll
      for (int m = 0; m < 8; ++m) {
        int rl = wr * 128 + m * 16 + lg * 4;
        unsigned int w0 = cvtpk(acc[m][n][0] + bv, acc[m][n][1] + bv);
        unsigned int w1 = cvtpk(acc[m][n][2] + bv, acc[m][n][3] + bv);
        uint2v pk = {w0, w1};
        *(uint2v*)(smem + cl * 512 + ((rl * 2) ^ ((cl & 7) << 4))) = pk;
      }
    }
    LGKM0();
    BAR();
    int t0_abs = bm * 256;
    int bq_ = t0_abs >> 11, t0 = t0_abs & 2047;
    int h0 = (bn * 256 - 4096) >> 7;  // first of 2 heads in this block
#pragma unroll
    for (int i = 0; i < 16; ++i) {
      int dloc = i * 16 + wid * 2 + hi;  // 0..255
      short8 vrow = *(const short8*)(smem + dloc * 512 + ((l31 * 16) ^ ((dloc & 7) << 4)));
      int bh_ = bq_ * 16 + h0 + (dloc >> 7);
      int d = dloc & 127;
      *(short8*)(vtb + ((size_t)bh_ * 128 + d) * 2048 + t0 + l31 * 8) = vrow;
    }
  } else {
    // ---- q/k block: direct scatter ----
#pragma unroll
    for (int n = 0; n < 4; ++n) {
      int col = bn * 256 + wc * 64 + n * 16 + l15;  // [0,4096)
      float bv = bias[col];
      int which = col >> 11;       // 0=q 1=k (block-uniform)
      int h = (col & 2047) >> 7;
      int d = col & 127;
#pragma unroll
      for (int m = 0; m < 8; ++m) {
#pragma unroll
        for (int g = 0; g < 4; ++g) {
          int row = bm * 256 + wr * 128 + m * 16 + lg * 4 + g;  // [0,8192)
          int b = row >> 11, t = row & 2047;
          float r = acc[m][n][g] + bv;
          if (which == 0) r *= QSCALE;
          unsigned short val = f2bf(r);
          size_t bhi = (size_t)(b * 16 + h);
          if (which == 0) qb[(bhi * 2048 + t) * 128 + d] = val;
          else            kb[(bhi * 2048 + t) * 128 + d] = val;
        }
      }
    }
  }
}

// ---------------- Proj GEMM 256^2: fp32 output + bias ----------------
__global__ __launch_bounds__(512, 2) void gemm_proj256_kernel(const unsigned short* __restrict__ A,
                                                              const unsigned short* __restrict__ Bt,
                                                              const float* __restrict__ bias,
                                                              float* __restrict__ out) {
  extern __shared__ char smem[];
  int wg = blockIdx.x;
  int bm = wg >> 3, bn = wg & 7;  // one bn column per XCD; B-panel L2-resident
  int tid = threadIdx.x;

  f32x4 acc[8][4];
  f32x4 zero = {0.f, 0.f, 0.f, 0.f};
#pragma unroll
  for (int m = 0; m < 8; ++m)
#pragma unroll
    for (int n = 0; n < 4; ++n) acc[m][n] = zero;

  gemm256_mainloop(A + (size_t)bm * 256 * 2048, Bt + (size_t)bn * 256 * 2048, 2048, tid, smem, acc);

  int wid = tid >> 6, lane = tid & 63;
  int wr = wid >> 2, wc = wid & 3, lg = lane >> 4, l15 = lane & 15;
#pragma unroll
  for (int n = 0; n < 4; ++n) {
    int col = bn * 256 + wc * 64 + n * 16 + l15;
    float bv = bias[col];
#pragma unroll
    for (int m = 0; m < 8; ++m) {
#pragma unroll
      for (int g = 0; g < 4; ++g) {
        int row = bm * 256 + wr * 128 + m * 16 + lg * 4 + g;
        out[(size_t)row * 2048 + col] = acc[m][n][g] + bv;
      }
    }
  }
}

// ---------------- Flash attention: paired q-tiles, double-buffered K/V, 2-phase pipeline ----------------
__global__ __launch_bounds__(256) void attn_kernel(const unsigned short* __restrict__ qb,
                                                   const unsigned short* __restrict__ kb,
                                                   const unsigned short* __restrict__ vtb,
                                                   unsigned short* __restrict__ ob) {
  extern __shared__ char asmem[];
  int pairi = blockIdx.x;  // 0..7
  int bh = blockIdx.y;
  int b = bh >> 4, h = bh & 15;
  int tid = threadIdx.x, wid = tid >> 6, lane = tid & 63;
  int l31 = lane & 31, hi = lane >> 5;

  const unsigned short* Q  = qb  + (size_t)bh * 2048 * 128;
  const unsigned short* K  = kb  + (size_t)bh * 2048 * 128;
  const unsigned short* Vt = vtb + (size_t)bh * 128 * 2048;

#pragma unroll 1
  for (int pass = 0; pass < 2; ++pass) {
    int qt = pass == 0 ? (15 - pairi) : pairi;
    int NT = 2 * qt + 2;
    int qbase = qt * 128 + wid * 32;
    int qrow = qbase + l31;

    short8 qf[8];
#pragma unroll
    for (int kc = 0; kc < 8; ++kc)
      qf[kc] = *(const short8*)(Q + (size_t)qrow * 128 + kc * 16 + hi * 8);

    f32x16 o0 = {}, o1 = {}, o2 = {}, o3 = {};  // O^T[d][q=l31]
    float m_run = -1e30f, l_run = 0.f;

    // prologue: stage tile 0 into buf0
    {
      char* kb_ = asmem;
#pragma unroll
      for (int it = 0; it < 4; ++it) {
        int li = it * 256 + tid;
        int r = li >> 4, c = li & 15;
        GLOAD16(K + (size_t)r * 128 + (c ^ (r & 7)) * 8, kb_ + li * 16);
      }
#pragma unroll
      for (int it = 0; it < 4; ++it) {
        int li = it * 256 + tid;
        int r = li >> 3, c = li & 7;
        GLOAD16(Vt + (size_t)r * 2048 + (c ^ (r & 7)) * 8, kb_ + 16384 + li * 16);
      }
    }
    VMCNT0();
    BAR();

#pragma unroll 1
    for (int kt = 0; kt < NT; ++kt) {
      char* cb = asmem + ((kt & 1) << 15);
      // stage next tile into the other buffer (hidden under this tile's compute)
      if (kt + 1 < NT) {
        char* nb = asmem + (((kt + 1) & 1) << 15);
        int kt1 = kt + 1;
#pragma unroll
        for (int it = 0; it < 4; ++it) {
          int li = it * 256 + tid;
          int r = li >> 4, c = li & 15;
          GLOAD16(K + (size_t)(kt1 * 64 + r) * 128 + (c ^ (r & 7)) * 8, nb + li * 16);
        }
#pragma unroll
        for (int it = 0; it < 4; ++it) {
          int li = it * 256 + tid;
          int r = li >> 3, c = li & 7;
          GLOAD16(Vt + (size_t)r * 2048 + kt1 * 64 + (c ^ (r & 7)) * 8, nb + 16384 + li * 16);
        }
      }

      bool active = (kt * 64 <= qbase + 31);  // wave-uniform
      if (active) {
        const char* k_l = cb;
        const char* v_l = cb + 16384;

        f32x16 s0v = {}, s1v = {};
        PRIO(1);
#pragma unroll
        for (int kc = 0; kc < 8; ++kc) {
          int cg = kc * 2 + hi;
          int sw = l31 & 7;
          short8 kf0 = *(const short8*)(k_l + l31 * 256 + ((cg ^ sw) * 16));
          s0v = __builtin_amdgcn_mfma_f32_32x32x16_bf16(kf0, qf[kc], s0v, 0, 0, 0);
          short8 kf1 = *(const short8*)(k_l + (32 + l31) * 256 + ((cg ^ sw) * 16));
          s1v = __builtin_amdgcn_mfma_f32_32x32x16_bf16(kf1, qf[kc], s1v, 0, 0, 0);
        }
        PRIO(0);

        if (kt * 64 + 63 > qbase) {
          int kvb = kt * 64 + 4 * hi;
#pragma unroll
          for (int r = 0; r < 16; ++r) {
            int kv = kvb + (r & 3) + 8 * (r >> 2);
            if (kv > qrow) s0v[r] = -1e30f;
            if (kv + 32 > qrow) s1v[r] = -1e30f;
          }
        }

        float tmax[16];
#pragma unroll
        for (int i = 0; i < 16; ++i) tmax[i] = fmaxf(s0v[i], s1v[i]);
#pragma unroll
        for (int st = 8; st >= 1; st >>= 1)
#pragma unroll
          for (int i = 0; i < st; ++i) tmax[i] = fmaxf(tmax[i], tmax[i + st]);
        float pmax = fmaxf(tmax[0], __shfl_xor(tmax[0], 32));

        if (!__all(pmax <= m_run + 8.0f)) {
          float mn = fmaxf(m_run, pmax);
          float alpha = exp2f(m_run - mn);
          m_run = mn; l_run *= alpha;
          o0 *= alpha; o1 *= alpha; o2 *= alpha; o3 *= alpha;
        }

#pragma unroll
        for (int i = 0; i < 16; ++i) {
          s0v[i] = exp2f(s0v[i] - m_run);
          s1v[i] = exp2f(s1v[i] - m_run);
        }
        float tsum[16];
#pragma unroll
        for (int i = 0; i < 16; ++i) tsum[i] = s0v[i] + s1v[i];
#pragma unroll
        for (int st = 8; st >= 1; st >>= 1)
#pragma unroll
          for (int i = 0; i < st; ++i) tsum[i] += tsum[i + st];
        float rsum = tsum[0] + __shfl_xor(tsum[0], 32);
        l_run += rsum;

#define BUILD_PA(sv, base, out)                                                \
        {                                                                      \
          unsigned int a_ = cvtpk(sv[base + 0], sv[base + 1]);                 \
          unsigned int c_ = cvtpk(sv[base + 2], sv[base + 3]);                 \
          unsigned int b_ = cvtpk(sv[base + 4], sv[base + 5]);                 \
          unsigned int d_ = cvtpk(sv[base + 6], sv[base + 7]);                 \
          uint2v r0_ = __builtin_amdgcn_permlane32_swap(a_, b_, false, false); \
          uint2v r1_ = __builtin_amdgcn_permlane32_swap(c_, d_, false, false); \
          union { unsigned int u[4]; short8 v; } uu_;                          \
          uu_.u[0] = r0_[0]; uu_.u[1] = r1_[0]; uu_.u[2] = r0_[1]; uu_.u[3] = r1_[1]; \
          out = uu_.v;                                                         \
        }
        short8 pa0, pa1, pa2, pa3;
        BUILD_PA(s0v, 0, pa0);
        BUILD_PA(s0v, 8, pa1);
        BUILD_PA(s1v, 0, pa2);
        BUILD_PA(s1v, 8, pa3);
#undef BUILD_PA

        PRIO(1);
#define PV_STEP(ovar, dt)                                                          \
        {                                                                          \
          int rv_ = dt * 32 + l31;                                                 \
          const char* vb_ = v_l + rv_ * 128;                                       \
          int sw_ = rv_ & 7;                                                       \
          short8 v0_ = *(const short8*)(vb_ + (((0 + hi) ^ sw_) * 16));            \
          ovar = __builtin_amdgcn_mfma_f32_32x32x16_bf16(v0_, pa0, ovar, 0, 0, 0); \
          short8 v1_ = *(const short8*)(vb_ + (((2 + hi) ^ sw_) * 16));            \
          ovar = __builtin_amdgcn_mfma_f32_32x32x16_bf16(v1_, pa1, ovar, 0, 0, 0); \
          short8 v2_ = *(const short8*)(vb_ + (((4 + hi) ^ sw_) * 16));            \
          ovar = __builtin_amdgcn_mfma_f32_32x32x16_bf16(v2_, pa2, ovar, 0, 0, 0); \
          short8 v3_ = *(const short8*)(vb_ + (((6 + hi) ^ sw_) * 16));            \
          ovar = __builtin_amdgcn_mfma_f32_32x32x16_bf16(v3_, pa3, ovar, 0, 0, 0); \
        }
        PV_STEP(o0, 0)
        PV_STEP(o1, 1)
        PV_STEP(o2, 2)
        PV_STEP(o3, 3)
#undef PV_STEP
        PRIO(0);
      }

      VMCNT0();  // next tile's stage complete (issued ~1 compute-phase ago)
      BAR();
    }

    float inv = 1.0f / l_run;
    size_t orow = (size_t)(b * 2048 + qt * 128 + wid * 32 + l31);
    unsigned short* ob_p = ob + orow * 2048 + h * 128;
#define STORE_DT(ovar, dt)                                                         \
    {                                                                              \
      _Pragma("unroll")                                                            \
      for (int rq = 0; rq < 4; ++rq) {                                             \
        unsigned int w0 = cvtpk(ovar[rq * 4 + 0] * inv, ovar[rq * 4 + 1] * inv);   \
        unsigned int w1 = cvtpk(ovar[rq * 4 + 2] * inv, ovar[rq * 4 + 3] * inv);   \
        uint2v st = {w0, w1};                                                      \
        *(uint2v*)(ob_p + dt * 32 + rq * 8 + 4 * hi) = st;                         \
      }                                                                            \
    }
    STORE_DT(o0, 0)
    STORE_DT(o1, 1)
    STORE_DT(o2, 2)
    STORE_DT(o3, 3)
#undef STORE_DT
  }
}

// ---------------- launch ----------------
extern "C" void kernel_launch(void* const* d_in, const int* in_sizes, int n_in,
                              void* d_out, int out_size, void* d_ws, size_t ws_size,
                              hipStream_t stream) {
  const float* x     = (const float*)d_in[0];
  const float* Wqkv  = (const float*)d_in[1];
  const float* bqkv  = (const float*)d_in[2];
  const float* Wproj = (const float*)d_in[3];
  const float* bproj = (const float*)d_in[4];
  float* out = (float*)d_out;

  char* ws = (char*)d_ws;
  unsigned short* x_bf   = (unsigned short*)ws;                         // 32MB, reused as attn_out
  unsigned short* wqkvt  = (unsigned short*)(ws + 33554432);            // 24MB
  unsigned short* wprojt = (unsigned short*)(ws + 33554432 + 25165824); // 8MB
  unsigned short* qb     = (unsigned short*)(ws + 67108864);            // 32MB (pre-scaled)
  unsigned short* kb     = (unsigned short*)(ws + 100663296);           // 32MB
  unsigned short* vtb    = (unsigned short*)(ws + 134217728);           // 32MB [bh][d][t]

  (void)hipFuncSetAttribute((const void*)gemm_qkv256_kernel,
                            hipFuncAttributeMaxDynamicSharedMemorySize, 131072);
  (void)hipFuncSetAttribute((const void*)gemm_proj256_kernel,
                            hipFuncAttributeMaxDynamicSharedMemorySize, 131072);
  (void)hipFuncSetAttribute((const void*)attn_kernel,
                            hipFuncAttributeMaxDynamicSharedMemorySize, 65536);

  cast_bf16_kernel<<<16384, 256, 0, stream>>>(x, x_bf);
  transpose_cast_kernel<<<dim3(192, 64), dim3(32, 8), 0, stream>>>(Wqkv, wqkvt, 2048, 6144);
  transpose_cast_kernel<<<dim3(64, 64), dim3(32, 8), 0, stream>>>(Wproj, wprojt, 2048, 2048);
  gemm_qkv256_kernel<<<768, 512, 131072, stream>>>(x_bf, wqkvt, bqkv, qb, kb, vtb);
  attn_kernel<<<dim3(8, 64), 256, 65536, stream>>>(qb, kb, vtb, x_bf /* attn_out */);
  gemm_proj256_kernel<<<256, 512, 131072, stream>>>(x_bf, wprojt, bproj, out);
}